// Round 1
// baseline (283.888 us; speedup 1.0000x reference)
//
#include <hip/hip_runtime.h>
#include <hip/hip_bf16.h>
#include <cstdint>
#include <cstddef>

typedef __attribute__((ext_vector_type(4))) float f32x4;
typedef __attribute__((ext_vector_type(8))) short bf16x8;

#define DEVI static __device__ __forceinline__

DEVI unsigned short f2bf(float f) {
  union { float f; unsigned int u; } v; v.f = f;
  unsigned int u = v.u;
  unsigned int r = (u + 0x7fffu + ((u >> 16) & 1u)) >> 16;
  return (unsigned short)r;
}

// packed fp32 pair -> bf16x2 in one VALU op (RNE)
DEVI unsigned int cvt_pk(float lo, float hi) {
  unsigned int r;
  asm("v_cvt_pk_bf16_f32 %0, %1, %2" : "=v"(r) : "v"(lo), "v"(hi));
  return r;
}

DEVI f32x4 mfma16(bf16x8 a, bf16x8 b, f32x4 c) {
  return __builtin_amdgcn_mfma_f32_16x16x32_bf16(a, b, c, 0, 0, 0);
}

// global -> LDS direct staging, 16B per lane (wave-uniform LDS base).
#define GLDS(gp, lp) __builtin_amdgcn_global_load_lds(                         \
    (const __attribute__((address_space(1))) void*)(const void*)(gp),          \
    (__attribute__((address_space(3))) void*)(void*)(lp), 16, 0, 0)

#define SBAR() asm volatile("s_barrier" ::: "memory")
#define WV(n) asm volatile("s_waitcnt vmcnt(" #n ")" ::: "memory")
#define FORCE4(x) asm volatile("" : "+v"(x))

// ---------------------------------------------------------------- convert ---
__global__ void convert_kernel(const float* __restrict__ hidden,
                               const float* __restrict__ qkv_w,
                               const float* __restrict__ o_w,
                               const float* __restrict__ scaling,
                               unsigned short* __restrict__ hbf,
                               unsigned short* __restrict__ wbf,
                               unsigned short* __restrict__ obf,
                               float* __restrict__ qscale) {
  int tid = blockIdx.x * blockDim.x + threadIdx.x;
  int nt = gridDim.x * blockDim.x;
  if (tid < 64) {
    float x = scaling[tid];
    float sp = (x > 20.f) ? x : log1pf(__expf(x));
    // (1.442695041/8)*softplus, times log2e so softmax can use exp2 directly.
    qscale[tid] = 0.1803368801243369f * 1.4426950408889634f * sp;
  }
  for (int i = tid; i < 1048576; i += nt) {
    float4 v = ((const float4*)hidden)[i];
    ushort4 o = { f2bf(v.x), f2bf(v.y), f2bf(v.z), f2bf(v.w) };
    ((ushort4*)hbf)[i] = o;
  }
  for (int i = tid; i < 393216; i += nt) {
    float4 v = ((const float4*)qkv_w)[i];
    ushort4 o = { f2bf(v.x), f2bf(v.y), f2bf(v.z), f2bf(v.w) };
    ((ushort4*)wbf)[i] = o;
  }
  for (int i = tid; i < 262144; i += nt) {
    float4 v = ((const float4*)o_w)[i];
    ushort4 o = { f2bf(v.x), f2bf(v.y), f2bf(v.z), f2bf(v.w) };
    ((ushort4*)obf)[i] = o;
  }
}

// ------------------------------------------------------------------- GEMM ---
template <int EPI>
__global__ __launch_bounds__(256, 2) void gemm_kernel(
    const unsigned short* __restrict__ A,
    const unsigned short* __restrict__ Bw,
    const float* __restrict__ bias,
    const float* __restrict__ qscale,
    unsigned short* __restrict__ oq,
    unsigned short* __restrict__ okv,
    unsigned short* __restrict__ ovt,
    float* __restrict__ of) {
  __shared__ __align__(16) unsigned short sA[128 * 64];
  __shared__ __align__(16) unsigned short sB[128 * 64];
  const int t = threadIdx.x, lane = t & 63, w = t >> 6;
  const int l15 = lane & 15, lg = lane >> 4;
  const int m0 = blockIdx.y * 128, n0 = blockIdx.x * 128;
  const int wr = w >> 1, wc = w & 1;

  f32x4 acc[4][4] = {};

  for (int kb = 0; kb < 1024; kb += 64) {
    __syncthreads();
#pragma unroll
    for (int i = 0; i < 4; i++) {
      int idx = i * 256 + w * 64 + lane;
      int row = idx >> 3;
      int cg = (idx & 7) ^ (row & 7);
      GLDS(A + (size_t)(m0 + row) * 1024 + kb + cg * 8, sA + (i * 256 + w * 64) * 8);
      GLDS(Bw + (size_t)(n0 + row) * 1024 + kb + cg * 8, sB + (i * 256 + w * 64) * 8);
    }
    __syncthreads();
    bf16x8 af[4][2], bfr[4][2];
#pragma unroll
    for (int rt = 0; rt < 4; rt++) {
      int row = wr * 64 + rt * 16 + l15;
#pragma unroll
      for (int kk = 0; kk < 2; kk++) {
        int c = (kk * 4 + lg) ^ (row & 7);
        af[rt][kk] = *(const bf16x8*)((const char*)sA + row * 128 + c * 16);
      }
      int rowb = wc * 64 + rt * 16 + l15;
#pragma unroll
      for (int kk = 0; kk < 2; kk++) {
        int c = (kk * 4 + lg) ^ (rowb & 7);
        bfr[rt][kk] = *(const bf16x8*)((const char*)sB + rowb * 128 + c * 16);
      }
    }
#pragma unroll
    for (int kk = 0; kk < 2; kk++)
#pragma unroll
      for (int rt = 0; rt < 4; rt++)
#pragma unroll
        for (int ct = 0; ct < 4; ct++)
          acc[rt][ct] = mfma16(af[rt][kk], bfr[ct][kk], acc[rt][ct]);
  }

#pragma unroll
  for (int rt = 0; rt < 4; rt++) {
#pragma unroll
    for (int ct = 0; ct < 4; ct++) {
      int n = n0 + wc * 64 + ct * 16 + l15;
      float bv = bias[n];
#pragma unroll
      for (int jj = 0; jj < 4; jj++) {
        int m = m0 + wr * 64 + rt * 16 + lg * 4 + jj;
        float v = acc[rt][ct][jj] + bv;
        if (EPI == 1) {
          int b = m >> 11, s = m & 2047;
          if (n < 1024) {  // q: scaled, [b][h][s][d]
            int h = n >> 6, d = n & 63;
            v *= qscale[d];
            oq[(((size_t)(b * 16 + h) * 2048 + s) << 6) + d] = f2bf(v);
          } else if (n < 1280) {  // k: [b][kv][s][d]
            int kv = (n - 1024) >> 6, d = n & 63;
            okv[(((size_t)(b * 4 + kv) * 2048 + s) << 6) + d] = f2bf(v);
          } else {  // v transposed: [b][kv][d][s]
            int kv = (n - 1280) >> 6, d = n & 63;
            ovt[(((size_t)((b * 4 + kv) * 64 + d)) << 11) + s] = f2bf(v);
          }
        } else {
          // final output: write-once fp32, never re-read -> non-temporal
          __builtin_nontemporal_store(v, &of[(size_t)m * 1024 + n]);
        }
      }
    }
  }
}

// -------------------------------------------------------------- attention ---
// Fused-pair: block = (bh, p) handles q-tiles A=p and B=31-p with ONE K-sweep
// per pass (B's extent covers A's). Swapped-operand MFMA (lane owns a q-row),
// per-lane Q loads, dwordx4 NT stores, cvt_pk packing.
//
// This revision:
//  * ALL zero tiles (31 per block: A cols qtA+1..31, B cols NB..31) are stored
//    in pass 1 (2 tiles/iter, fits since NB>=17) -> pass 1's idle store pipe
//    carries ~248 MB; pass 2 drops to ~289 MB. Counted vmcnt never drains.
//  * Shared-fragment dual-half MFMA: one ak (K) read feeds both A and B QK
//    MFMAs, one bv (V) read feeds both PV MFMAs -> LDS b128 traffic ~halved.
//    Needs two P buffers (sP[8][2048]).
//  * Score stores are non-temporal (write-once stream; don't thrash L2).
__global__ __launch_bounds__(256, 2) void attn_kernel(
    const unsigned short* __restrict__ q_ws,
    const unsigned short* __restrict__ k_ws,
    const unsigned short* __restrict__ v_ws,
    float* __restrict__ scores,
    unsigned short* __restrict__ attn_bf) {
  __shared__ __align__(16) unsigned short sK[2][4096];
  __shared__ __align__(16) unsigned short sVT[2][4096];
  __shared__ __align__(16) unsigned char sP[8][2048];

  const int t = threadIdx.x, lane = t & 63, w = t >> 6;
  const int l15 = lane & 15, lg = lane >> 4;
  int bid = blockIdx.x;
  int bh = bid & 31;            // b*16+h
  int p = bid >> 5;             // 0..15
  int b = bh >> 4, h = bh & 15, kv = h >> 2;
  const int qtA = p, qtB = 31 - p;
  const int NB = qtB + 1;       // 17..32 k-tiles (covers A's p+1)

  const unsigned short* Kp = k_ws + ((size_t)(b * 4 + kv) * 2048) * 64;
  const unsigned short* Vp = v_ws + ((size_t)(b * 4 + kv) * 64) * 2048;  // [d][s]
  const int qrA = qtA * 64 + w * 16 + l15;   // this lane's A q-row
  const int qrB = qtB * 64 + w * 16 + l15;   // this lane's B q-row

  // per-lane Q fragments (compiler-tracked; FORCE4 drains them before staging)
  bf16x8 aqA[2], aqB[2];
  {
    const unsigned short* qa = q_ws + ((size_t)bh * 2048 + qrA) * 64;
    const unsigned short* qb = q_ws + ((size_t)bh * 2048 + qrB) * 64;
    aqA[0] = *(const bf16x8*)(qa + lg * 8);
    aqA[1] = *(const bf16x8*)(qa + 32 + lg * 8);
    aqB[0] = *(const bf16x8*)(qb + lg * 8);
    aqB[1] = *(const bf16x8*)(qb + 32 + lg * 8);
    FORCE4(*(f32x4*)&aqA[0]); FORCE4(*(f32x4*)&aqA[1]);
    FORCE4(*(f32x4*)&aqB[0]); FORCE4(*(f32x4*)&aqB[1]);
  }

  auto stageK = [&](int kt, int bufi) {  // 2 GLDS per wave
#pragma unroll
    for (int i = 0; i < 2; i++) {
      int idx = i * 256 + w * 64 + lane;
      int row = idx >> 3;
      int cg = (idx & 7) ^ (row & 7);
      GLDS(Kp + (size_t)(kt * 64 + row) * 64 + cg * 8, sK[bufi] + (i * 256 + w * 64) * 8);
    }
  };
  auto stageVT = [&](int kt, int bufi) {  // 2 GLDS per wave
#pragma unroll
    for (int i = 0; i < 2; i++) {
      int idx = i * 256 + w * 64 + lane;
      int row = idx >> 3;
      int cg = (idx & 7) ^ (row & 7);
      GLDS(Vp + (size_t)row * 2048 + kt * 64 + cg * 8, sVT[bufi] + (i * 256 + w * 64) * 8);
    }
  };
  // swapped QK^T: K rows as A, Q as B -> acc[ct][j] = S[q=l15][k0+ct*16+lg*4+j]
  auto qk_tile = [&](const unsigned short* kb, const bf16x8(&aq)[2], f32x4(&acc)[4]) {
#pragma unroll
    for (int ct = 0; ct < 4; ct++) {
      int row = ct * 16 + l15;
#pragma unroll
      for (int kk = 0; kk < 2; kk++) {
        int c = (kk * 4 + lg) ^ (row & 7);
        bf16x8 ak = *(const bf16x8*)((const char*)kb + row * 128 + c * 16);
        acc[ct] = mfma16(ak, aq[kk], acc[ct]);
      }
    }
  };

  // zero-tile store: zi in [0,31). zi < 31-p -> A-row tile at col-tile p+1+zi
  // (covers qtA+1..31); else B-row tile at col-tile zi+1 (covers NB..31).
  auto zstore = [&](int zi) {
    int zc = (zi < 31 - p) ? (p + 1 + zi) : (zi + 1);
    int rt = (zi < 31 - p) ? qtA : qtB;
    float* rowp = scores + ((size_t)bh * 2048 + rt * 64 + w * 16 + l15) * 2048
                  + zc * 64 + lg * 4;
    f32x4 z = {0.f, 0.f, 0.f, 0.f};
#pragma unroll
    for (int ct = 0; ct < 4; ct++)
      __builtin_nontemporal_store(z, (f32x4*)(rowp + ct * 16));
  };

  // ---- pass 1: rowsums for BOTH halves + all zero tiles, one K sweep ----
  // store schedule: iter n stores zero tiles zi=2n,2n+1 (<31): 8 stores/lane
  // for n<=14, 4 at n==15, 0 after. vmcnt at iter n needs G_n done; younger
  // ops = S_{n-1} + G_{n+1}(2): n==0 -> 2; 1<=n<=15 -> 10; n==16 -> 6;
  // n>=17 -> 2. Last iter (no G_{n+1}): n==16 -> 4 else 0.
  stageK(0, 0);
  float rsA = 0.f, rsB = 0.f;
  for (int n = 0; n < NB; n++) {
    if (n + 1 < NB) {
      stageK(n + 1, (n + 1) & 1);
      if (n == 0) { WV(2); }
      else if (n <= 15) { WV(10); }
      else if (n == 16) { WV(6); }
      else { WV(2); }
    } else {
      if (n == 16) { WV(4); } else { WV(0); }
    }
    SBAR();
    const unsigned short* kb = sK[n & 1];
    bool doA = (n <= qtA);
    f32x4 aB[4] = {};
    if (doA) {
      f32x4 aA[4] = {};
#pragma unroll
      for (int ct = 0; ct < 4; ct++) {
        int row = ct * 16 + l15;
#pragma unroll
        for (int kk = 0; kk < 2; kk++) {
          int c = (kk * 4 + lg) ^ (row & 7);
          bf16x8 ak = *(const bf16x8*)((const char*)kb + row * 128 + c * 16);
          aB[ct] = mfma16(ak, aqB[kk], aB[ct]);
          aA[ct] = mfma16(ak, aqA[kk], aA[ct]);
        }
      }
      if (n < qtA) {
#pragma unroll
        for (int ct = 0; ct < 4; ct++)
#pragma unroll
          for (int j = 0; j < 4; j++) rsA += __builtin_amdgcn_exp2f(aA[ct][j]);
      } else {
#pragma unroll
        for (int ct = 0; ct < 4; ct++) {
          int kb0 = n * 64 + ct * 16 + lg * 4;
#pragma unroll
          for (int j = 0; j < 4; j++)
            rsA += (kb0 + j <= qrA) ? __builtin_amdgcn_exp2f(aA[ct][j]) : 0.f;
        }
      }
    } else {
      qk_tile(kb, aqB, aB);
    }
    if (n < NB - 1) {
#pragma unroll
      for (int ct = 0; ct < 4; ct++)
#pragma unroll
        for (int j = 0; j < 4; j++) rsB += __builtin_amdgcn_exp2f(aB[ct][j]);
    } else {
#pragma unroll
      for (int ct = 0; ct < 4; ct++) {
        int kb0 = n * 64 + ct * 16 + lg * 4;
#pragma unroll
        for (int j = 0; j < 4; j++)
          rsB += (kb0 + j <= qrB) ? __builtin_amdgcn_exp2f(aB[ct][j]) : 0.f;
      }
    }
    // zero tiles for this iteration (overlap the otherwise-idle store pipe)
    int zi0 = 2 * n;
    if (zi0 < 31) zstore(zi0);
    if (zi0 + 1 < 31) zstore(zi0 + 1);
    SBAR();
  }
  rsA += __shfl_xor(rsA, 16); rsA += __shfl_xor(rsA, 32);
  rsB += __shfl_xor(rsB, 16); rsB += __shfl_xor(rsB, 32);
  float rinvA = 1.0f / rsA, rinvB = 1.0f / rsB;

  // ---- pass 2: P stores + PV for both halves (zeros already done) ----
  // per-iter score stores m_n = 4 + 4*(n<=qtA). vmcnt at iter n needs G_n;
  // younger = S_{n-1}(m_{n-1}) + G_{n+1}(4 if staged).
  stageK(0, 0); stageVT(0, 0);
  f32x4 accoA[4] = {}, accoB[4] = {};
  unsigned char* myPB = &sP[w][0];
  unsigned char* myPA = &sP[4 + w][0];
  const int xr = (l15 & 7) << 4;
  float* SpA = scores + ((size_t)bh * 2048 + qtA * 64) * 2048;
  float* SpB = scores + ((size_t)bh * 2048 + qtB * 64) * 2048;

  for (int n = 0; n < NB; n++) {
    bool doA = (n <= qtA);
    if (n + 1 < NB) { stageK(n + 1, (n + 1) & 1); stageVT(n + 1, (n + 1) & 1); }
    if (n == 0) { WV(4); }
    else if (n + 1 < NB) { if (n - 1 <= qtA) { WV(12); } else { WV(8); } }
    else { if (n - 1 <= qtA) { WV(8); } else { WV(4); } }
    SBAR();
    const unsigned short* kb = sK[n & 1];
    const unsigned short* vt = sVT[n & 1];
    int k0 = n * 64;

    // QK for both halves, sharing the ak fragment reads
    f32x4 aB[4] = {}, aA[4] = {};
    if (doA) {
#pragma unroll
      for (int ct = 0; ct < 4; ct++) {
        int row = ct * 16 + l15;
#pragma unroll
        for (int kk = 0; kk < 2; kk++) {
          int c = (kk * 4 + lg) ^ (row & 7);
          bf16x8 ak = *(const bf16x8*)((const char*)kb + row * 128 + c * 16);
          aB[ct] = mfma16(ak, aqB[kk], aB[ct]);
          aA[ct] = mfma16(ak, aqA[kk], aA[ct]);
        }
      }
    } else {
      qk_tile(kb, aqB, aB);
    }

    // ---- B finish: softmax, NT score store, pack to myPB ----
    if (n == NB - 1) {
#pragma unroll
      for (int ct = 0; ct < 4; ct++) {
        int kb0 = k0 + ct * 16 + lg * 4;
#pragma unroll
        for (int j = 0; j < 4; j++)
          aB[ct][j] = (kb0 + j <= qrB) ? __builtin_amdgcn_exp2f(aB[ct][j]) * rinvB : 0.f;
      }
    } else {
#pragma unroll
      for (int ct = 0; ct < 4; ct++)
#pragma unroll
        for (int j = 0; j < 4; j++)
          aB[ct][j] = __builtin_amdgcn_exp2f(aB[ct][j]) * rinvB;
    }
    {
      float* srow = SpB + (size_t)(w * 16 + l15) * 2048 + k0 + lg * 4;
#pragma unroll
      for (int ct = 0; ct < 4; ct++)
        __builtin_nontemporal_store(aB[ct], (f32x4*)(srow + ct * 16));
#pragma unroll
      for (int ct = 0; ct < 4; ct++) {
        uint2 pw;
        pw.x = cvt_pk(aB[ct][0], aB[ct][1]);
        pw.y = cvt_pk(aB[ct][2], aB[ct][3]);
        *(uint2*)(myPB + l15 * 128 + ((ct * 32 + lg * 8) ^ xr)) = pw;
      }
    }

    // ---- A finish (only while A is active) ----
    if (doA) {
      if (n == qtA) {
#pragma unroll
        for (int ct = 0; ct < 4; ct++) {
          int kb0 = k0 + ct * 16 + lg * 4;
#pragma unroll
          for (int j = 0; j < 4; j++)
            aA[ct][j] = (kb0 + j <= qrA) ? __builtin_amdgcn_exp2f(aA[ct][j]) * rinvA : 0.f;
        }
      } else {
#pragma unroll
        for (int ct = 0; ct < 4; ct++)
#pragma unroll
          for (int j = 0; j < 4; j++)
            aA[ct][j] = __builtin_amdgcn_exp2f(aA[ct][j]) * rinvA;
      }
      float* srow = SpA + (size_t)(w * 16 + l15) * 2048 + k0 + lg * 4;
#pragma unroll
      for (int ct = 0; ct < 4; ct++)
        __builtin_nontemporal_store(aA[ct], (f32x4*)(srow + ct * 16));
#pragma unroll
      for (int ct = 0; ct < 4; ct++) {
        uint2 pw;
        pw.x = cvt_pk(aA[ct][0], aA[ct][1]);
        pw.y = cvt_pk(aA[ct][2], aA[ct][3]);
        *(uint2*)(myPA + l15 * 128 + ((ct * 32 + lg * 8) ^ xr)) = pw;
      }
    }

    // ---- PV, sharing the bv fragment reads across halves ----
    if (doA) {
#pragma unroll
      for (int kk = 0; kk < 2; kk++) {
        bf16x8 apB = *(const bf16x8*)(myPB + l15 * 128 + ((kk * 64 + lg * 16) ^ xr));
        bf16x8 apA = *(const bf16x8*)(myPA + l15 * 128 + ((kk * 64 + lg * 16) ^ xr));
#pragma unroll
        for (int ct = 0; ct < 4; ct++) {
          int vrow = ct * 16 + l15;
          int cv = (kk * 4 + lg) ^ (vrow & 7);
          bf16x8 bv = *(const bf16x8*)((const char*)vt + vrow * 128 + cv * 16);
          accoB[ct] = mfma16(bv, apB, accoB[ct]);
          accoA[ct] = mfma16(bv, apA, accoA[ct]);
        }
      }
    } else {
#pragma unroll
      for (int kk = 0; kk < 2; kk++) {
        bf16x8 apB = *(const bf16x8*)(myPB + l15 * 128 + ((kk * 64 + lg * 16) ^ xr));
#pragma unroll
        for (int ct = 0; ct < 4; ct++) {
          int vrow = ct * 16 + l15;
          int cv = (kk * 4 + lg) ^ (vrow & 7);
          bf16x8 bv = *(const bf16x8*)((const char*)vt + vrow * 128 + cv * 16);
          accoB[ct] = mfma16(bv, apB, accoB[ct]);
        }
      }
    }
    SBAR();
  }

  // O stores: lane holds O[q=l15][d=ct*16+lg*4+..] -> packed uint2
  {
    int mA = b * 2048 + qtA * 64 + w * 16 + l15;
    int mB = b * 2048 + qtB * 64 + w * 16 + l15;
    unsigned int* oA = (unsigned int*)(attn_bf + (size_t)mA * 1024 + h * 64);
    unsigned int* oB = (unsigned int*)(attn_bf + (size_t)mB * 1024 + h * 64);
#pragma unroll
    for (int ct = 0; ct < 4; ct++) {
      uint2 pa, pb;
      pa.x = cvt_pk(accoA[ct][0], accoA[ct][1]);
      pa.y = cvt_pk(accoA[ct][2], accoA[ct][3]);
      pb.x = cvt_pk(accoB[ct][0], accoB[ct][1]);
      pb.y = cvt_pk(accoB[ct][2], accoB[ct][3]);
      *(uint2*)(oA + (ct * 16 + lg * 4) / 2) = pa;
      *(uint2*)(oB + (ct * 16 + lg * 4) / 2) = pb;
    }
  }
}

// ----------------------------------------------------------------- launch ---
extern "C" void kernel_launch(void* const* d_in, const int* in_sizes, int n_in,
                              void* d_out, int out_size, void* d_ws, size_t ws_size,
                              hipStream_t stream) {
  const float* hidden  = (const float*)d_in[0];
  // d_in[1] = mask: causal by construction; applied analytically.
  const float* scaling = (const float*)d_in[2];
  const float* qkv_w   = (const float*)d_in[3];
  const float* qkv_b   = (const float*)d_in[4];
  const float* o_w     = (const float*)d_in[5];
  const float* o_b     = (const float*)d_in[6];

  float* scores = (float*)d_out;                                 // [2][16][2048][2048]
  float* outp   = (float*)d_out + (size_t)2 * 16 * 2048 * 2048;  // [4096][1024]

  char* ws = (char*)d_ws;
  unsigned short* hidden_bf = (unsigned short*)(ws + 0);          //  8 MB
  unsigned short* qkvw_bf   = (unsigned short*)(ws + 8388608);    //  3 MB
  unsigned short* ow_bf     = (unsigned short*)(ws + 11534336);   //  2 MB
  unsigned short* q_ws      = (unsigned short*)(ws + 13631488);   //  8 MB
  unsigned short* k_ws      = (unsigned short*)(ws + 22020096);   //  2 MB
  unsigned short* v_ws      = (unsigned short*)(ws + 24117248);   //  2 MB
  unsigned short* attn_bf   = (unsigned short*)(ws + 26214400);   //  8 MB
  float* qscale             = (float*)(ws + 34603008);            //  256 B

  convert_kernel<<<512, 256, 0, stream>>>(hidden, qkv_w, o_w, scaling,
                                          hidden_bf, qkvw_bf, ow_bf, qscale);
  gemm_kernel<1><<<dim3(12, 32), 256, 0, stream>>>(hidden_bf, qkvw_bf, qkv_b,
                                                   qscale, q_ws, k_ws, v_ws, nullptr);
  attn_kernel<<<512, 256, 0, stream>>>(q_ws, k_ws, v_ws, scores, attn_bf);
  gemm_kernel<2><<<dim3(8, 32), 256, 0, stream>>>(attn_bf, ow_bf, o_b, nullptr,
                                                  nullptr, nullptr, nullptr, outp);
}

// Round 2
// 221.395 us; speedup vs baseline: 1.2823x; 1.2823x over previous
//
#include <hip/hip_runtime.h>
#include <hip/hip_bf16.h>
#include <cstdint>
#include <cstddef>

typedef __attribute__((ext_vector_type(4))) float f32x4;
typedef __attribute__((ext_vector_type(8))) short bf16x8;

#define DEVI static __device__ __forceinline__

DEVI unsigned short f2bf(float f) {
  union { float f; unsigned int u; } v; v.f = f;
  unsigned int u = v.u;
  unsigned int r = (u + 0x7fffu + ((u >> 16) & 1u)) >> 16;
  return (unsigned short)r;
}

// packed fp32 pair -> bf16x2 in one VALU op (RNE)
DEVI unsigned int cvt_pk(float lo, float hi) {
  unsigned int r;
  asm("v_cvt_pk_bf16_f32 %0, %1, %2" : "=v"(r) : "v"(lo), "v"(hi));
  return r;
}

DEVI f32x4 mfma16(bf16x8 a, bf16x8 b, f32x4 c) {
  return __builtin_amdgcn_mfma_f32_16x16x32_bf16(a, b, c, 0, 0, 0);
}

// global -> LDS direct staging, 16B per lane (wave-uniform LDS base).
#define GLDS(gp, lp) __builtin_amdgcn_global_load_lds(                         \
    (const __attribute__((address_space(1))) void*)(const void*)(gp),          \
    (__attribute__((address_space(3))) void*)(void*)(lp), 16, 0, 0)

#define SBAR() asm volatile("s_barrier" ::: "memory")
#define WV(n) asm volatile("s_waitcnt vmcnt(" #n ")" ::: "memory")
#define FORCE4(x) asm volatile("" : "+v"(x))

// ---------------------------------------------------------------- convert ---
__global__ void convert_kernel(const float* __restrict__ hidden,
                               const float* __restrict__ qkv_w,
                               const float* __restrict__ o_w,
                               const float* __restrict__ scaling,
                               unsigned short* __restrict__ hbf,
                               unsigned short* __restrict__ wbf,
                               unsigned short* __restrict__ obf,
                               float* __restrict__ qscale) {
  int tid = blockIdx.x * blockDim.x + threadIdx.x;
  int nt = gridDim.x * blockDim.x;
  if (tid < 64) {
    float x = scaling[tid];
    float sp = (x > 20.f) ? x : log1pf(__expf(x));
    // (1.442695041/8)*softplus, times log2e so softmax can use exp2 directly.
    qscale[tid] = 0.1803368801243369f * 1.4426950408889634f * sp;
  }
  for (int i = tid; i < 1048576; i += nt) {
    float4 v = ((const float4*)hidden)[i];
    ushort4 o = { f2bf(v.x), f2bf(v.y), f2bf(v.z), f2bf(v.w) };
    ((ushort4*)hbf)[i] = o;
  }
  for (int i = tid; i < 393216; i += nt) {
    float4 v = ((const float4*)qkv_w)[i];
    ushort4 o = { f2bf(v.x), f2bf(v.y), f2bf(v.z), f2bf(v.w) };
    ((ushort4*)wbf)[i] = o;
  }
  for (int i = tid; i < 262144; i += nt) {
    float4 v = ((const float4*)o_w)[i];
    ushort4 o = { f2bf(v.x), f2bf(v.y), f2bf(v.z), f2bf(v.w) };
    ((ushort4*)obf)[i] = o;
  }
}

// ------------------------------------------------------------------- GEMM ---
template <int EPI>
__global__ __launch_bounds__(256, 2) void gemm_kernel(
    const unsigned short* __restrict__ A,
    const unsigned short* __restrict__ Bw,
    const float* __restrict__ bias,
    const float* __restrict__ qscale,
    unsigned short* __restrict__ oq,
    unsigned short* __restrict__ okv,
    unsigned short* __restrict__ ovt,
    float* __restrict__ of) {
  __shared__ __align__(16) unsigned short sA[128 * 64];
  __shared__ __align__(16) unsigned short sB[128 * 64];
  const int t = threadIdx.x, lane = t & 63, w = t >> 6;
  const int l15 = lane & 15, lg = lane >> 4;
  const int m0 = blockIdx.y * 128, n0 = blockIdx.x * 128;
  const int wr = w >> 1, wc = w & 1;

  f32x4 acc[4][4] = {};

  for (int kb = 0; kb < 1024; kb += 64) {
    __syncthreads();
#pragma unroll
    for (int i = 0; i < 4; i++) {
      int idx = i * 256 + w * 64 + lane;
      int row = idx >> 3;
      int cg = (idx & 7) ^ (row & 7);
      GLDS(A + (size_t)(m0 + row) * 1024 + kb + cg * 8, sA + (i * 256 + w * 64) * 8);
      GLDS(Bw + (size_t)(n0 + row) * 1024 + kb + cg * 8, sB + (i * 256 + w * 64) * 8);
    }
    __syncthreads();
    bf16x8 af[4][2], bfr[4][2];
#pragma unroll
    for (int rt = 0; rt < 4; rt++) {
      int row = wr * 64 + rt * 16 + l15;
#pragma unroll
      for (int kk = 0; kk < 2; kk++) {
        int c = (kk * 4 + lg) ^ (row & 7);
        af[rt][kk] = *(const bf16x8*)((const char*)sA + row * 128 + c * 16);
      }
      int rowb = wc * 64 + rt * 16 + l15;
#pragma unroll
      for (int kk = 0; kk < 2; kk++) {
        int c = (kk * 4 + lg) ^ (rowb & 7);
        bfr[rt][kk] = *(const bf16x8*)((const char*)sB + rowb * 128 + c * 16);
      }
    }
#pragma unroll
    for (int kk = 0; kk < 2; kk++)
#pragma unroll
      for (int rt = 0; rt < 4; rt++)
#pragma unroll
        for (int ct = 0; ct < 4; ct++)
          acc[rt][ct] = mfma16(af[rt][kk], bfr[ct][kk], acc[rt][ct]);
  }

#pragma unroll
  for (int rt = 0; rt < 4; rt++) {
#pragma unroll
    for (int ct = 0; ct < 4; ct++) {
      int n = n0 + wc * 64 + ct * 16 + l15;
      float bv = bias[n];
#pragma unroll
      for (int jj = 0; jj < 4; jj++) {
        int m = m0 + wr * 64 + rt * 16 + lg * 4 + jj;
        float v = acc[rt][ct][jj] + bv;
        if (EPI == 1) {
          int b = m >> 11, s = m & 2047;
          if (n < 1024) {  // q: scaled, [b][h][s][d]
            int h = n >> 6, d = n & 63;
            v *= qscale[d];
            oq[(((size_t)(b * 16 + h) * 2048 + s) << 6) + d] = f2bf(v);
          } else if (n < 1280) {  // k: [b][kv][s][d]
            int kv = (n - 1024) >> 6, d = n & 63;
            okv[(((size_t)(b * 4 + kv) * 2048 + s) << 6) + d] = f2bf(v);
          } else {  // v transposed: [b][kv][d][s]
            int kv = (n - 1280) >> 6, d = n & 63;
            ovt[(((size_t)((b * 4 + kv) * 64 + d)) << 11) + s] = f2bf(v);
          }
        } else {
          of[(size_t)m * 1024 + n] = v;
        }
      }
    }
  }
}

// -------------------------------------------------------------- attention ---
// Fused-pair: block = (bh, p) handles q-tiles A=p and B=31-p with ONE K-sweep
// per pass (B's extent covers A's). Swapped-operand MFMA (lane owns a q-row),
// per-lane Q loads, dwordx4 P stores, cvt_pk packing.
//
// This revision (SINGLE isolated change vs the 217us kernel): ALL 31 zero
// tiles per block are stored in pass 1 (2 tiles/iter; fits since NB>=17),
// using REGULAR stores (NT was the round-0 regression suspect: vmcnt retires
// in-order, so counted waits implicitly wait on older store acks; L2-acked
// regular stores keep that cheap). Pass 1's store pipe was previously idle;
// pass 2 drops from 537MB to ~289MB of stores.
__global__ __launch_bounds__(256, 2) void attn_kernel(
    const unsigned short* __restrict__ q_ws,
    const unsigned short* __restrict__ k_ws,
    const unsigned short* __restrict__ v_ws,
    float* __restrict__ scores,
    unsigned short* __restrict__ attn_bf) {
  __shared__ __align__(16) unsigned short sK[2][4096];
  __shared__ __align__(16) unsigned short sVT[2][4096];
  __shared__ __align__(16) unsigned char sP[4][2048];

  const int t = threadIdx.x, lane = t & 63, w = t >> 6;
  const int l15 = lane & 15, lg = lane >> 4;
  int bid = blockIdx.x;
  int bh = bid & 31;            // b*16+h
  int p = bid >> 5;             // 0..15
  int b = bh >> 4, h = bh & 15, kv = h >> 2;
  const int qtA = p, qtB = 31 - p;
  const int NB = qtB + 1;       // 17..32 k-tiles (covers A's p+1)

  const unsigned short* Kp = k_ws + ((size_t)(b * 4 + kv) * 2048) * 64;
  const unsigned short* Vp = v_ws + ((size_t)(b * 4 + kv) * 64) * 2048;  // [d][s]
  const int qrA = qtA * 64 + w * 16 + l15;   // this lane's A q-row
  const int qrB = qtB * 64 + w * 16 + l15;   // this lane's B q-row

  // per-lane Q fragments (compiler-tracked; FORCE4 drains them before staging)
  bf16x8 aqA[2], aqB[2];
  {
    const unsigned short* qa = q_ws + ((size_t)bh * 2048 + qrA) * 64;
    const unsigned short* qb = q_ws + ((size_t)bh * 2048 + qrB) * 64;
    aqA[0] = *(const bf16x8*)(qa + lg * 8);
    aqA[1] = *(const bf16x8*)(qa + 32 + lg * 8);
    aqB[0] = *(const bf16x8*)(qb + lg * 8);
    aqB[1] = *(const bf16x8*)(qb + 32 + lg * 8);
    FORCE4(*(f32x4*)&aqA[0]); FORCE4(*(f32x4*)&aqA[1]);
    FORCE4(*(f32x4*)&aqB[0]); FORCE4(*(f32x4*)&aqB[1]);
  }

  auto stageK = [&](int kt, int bufi) {  // 2 GLDS per wave
#pragma unroll
    for (int i = 0; i < 2; i++) {
      int idx = i * 256 + w * 64 + lane;
      int row = idx >> 3;
      int cg = (idx & 7) ^ (row & 7);
      GLDS(Kp + (size_t)(kt * 64 + row) * 64 + cg * 8, sK[bufi] + (i * 256 + w * 64) * 8);
    }
  };
  auto stageVT = [&](int kt, int bufi) {  // 2 GLDS per wave
#pragma unroll
    for (int i = 0; i < 2; i++) {
      int idx = i * 256 + w * 64 + lane;
      int row = idx >> 3;
      int cg = (idx & 7) ^ (row & 7);
      GLDS(Vp + (size_t)row * 2048 + kt * 64 + cg * 8, sVT[bufi] + (i * 256 + w * 64) * 8);
    }
  };
  // swapped QK^T: K rows as A, Q as B -> acc[ct][j] = S[q=l15][k0+ct*16+lg*4+j]
  auto qk_tile = [&](const unsigned short* kb, const bf16x8(&aq)[2], f32x4(&acc)[4]) {
#pragma unroll
    for (int ct = 0; ct < 4; ct++) {
      int row = ct * 16 + l15;
#pragma unroll
      for (int kk = 0; kk < 2; kk++) {
        int c = (kk * 4 + lg) ^ (row & 7);
        bf16x8 ak = *(const bf16x8*)((const char*)kb + row * 128 + c * 16);
        acc[ct] = mfma16(ak, aq[kk], acc[ct]);
      }
    }
  };

  // zero-tile store: zi in [0,31). zi < 31-p -> A-row tile at col-tile p+1+zi
  // (covers qtA+1..31); else B-row tile at col-tile zi+1 (covers NB..31).
  auto zstore = [&](int zi) {
    int zc = (zi < 31 - p) ? (p + 1 + zi) : (zi + 1);
    int rt = (zi < 31 - p) ? qtA : qtB;
    float* rowp = scores + ((size_t)bh * 2048 + rt * 64 + w * 16 + l15) * 2048
                  + zc * 64 + lg * 4;
    f32x4 z = {0.f, 0.f, 0.f, 0.f};
#pragma unroll
    for (int ct = 0; ct < 4; ct++)
      *(f32x4*)(rowp + ct * 16) = z;
  };

  // ---- pass 1: rowsums for BOTH halves + all zero tiles, one K sweep ----
  // stores/iter s_n: n<=14 -> 8, n==15 -> 4, n>=16 -> 0.
  // vmcnt at iter n (staging G_{n+1}): queue oldest-first
  // [G_n(2), S_{n-1}(s_{n-1}), G_{n+1}(2)] -> WV(s_{n-1}+2):
  // n==0 -> 2; 1..15 -> 10; 16 -> 6; >=17 -> 2.
  // Last iter (no staging): WV(s_{n-1}) -> 4 if n==16 else 0.
  stageK(0, 0);
  float rsA = 0.f, rsB = 0.f;
  for (int n = 0; n < NB; n++) {
    if (n + 1 < NB) {
      stageK(n + 1, (n + 1) & 1);
      if (n == 0) { WV(2); }
      else if (n <= 15) { WV(10); }
      else if (n == 16) { WV(6); }
      else { WV(2); }
    } else {
      if (n == 16) { WV(4); } else { WV(0); }
    }
    SBAR();
    const unsigned short* kb = sK[n & 1];
    {
      f32x4 acc[4] = {};
      qk_tile(kb, aqB, acc);
      if (n < NB - 1) {
#pragma unroll
        for (int ct = 0; ct < 4; ct++)
#pragma unroll
          for (int j = 0; j < 4; j++) rsB += __builtin_amdgcn_exp2f(acc[ct][j]);
      } else {
#pragma unroll
        for (int ct = 0; ct < 4; ct++) {
          int kb0 = n * 64 + ct * 16 + lg * 4;
#pragma unroll
          for (int j = 0; j < 4; j++)
            rsB += (kb0 + j <= qrB) ? __builtin_amdgcn_exp2f(acc[ct][j]) : 0.f;
        }
      }
    }
    if (n <= qtA) {
      f32x4 acc[4] = {};
      qk_tile(kb, aqA, acc);
      if (n < qtA) {
#pragma unroll
        for (int ct = 0; ct < 4; ct++)
#pragma unroll
          for (int j = 0; j < 4; j++) rsA += __builtin_amdgcn_exp2f(acc[ct][j]);
      } else {
#pragma unroll
        for (int ct = 0; ct < 4; ct++) {
          int kb0 = n * 64 + ct * 16 + lg * 4;
#pragma unroll
          for (int j = 0; j < 4; j++)
            rsA += (kb0 + j <= qrA) ? __builtin_amdgcn_exp2f(acc[ct][j]) : 0.f;
        }
      }
    }
    // zero tiles for this iteration (overlap the otherwise-idle store pipe)
    int zi0 = 2 * n;
    if (zi0 < 31) zstore(zi0);
    if (zi0 + 1 < 31) zstore(zi0 + 1);
    SBAR();
  }
  rsA += __shfl_xor(rsA, 16); rsA += __shfl_xor(rsA, 32);
  rsB += __shfl_xor(rsB, 16); rsB += __shfl_xor(rsB, 32);
  float rinvA = 1.0f / rsA, rinvB = 1.0f / rsB;

  // ---- pass 2: P stores + PV for both halves (zeros already done) ----
  // stores/iter: B(4) + A(4 if n<=qtA). vmcnt at iter n needs G_n retired;
  // queue [G_n(4), S_{n-1}(8 or 4), G_{n+1}(4 if staged)]:
  // n==0 -> 4; mid -> 12 if n-1<=qtA else 8; last -> 8 if n-1<=qtA else 4.
  stageK(0, 0); stageVT(0, 0);
  f32x4 accoA[4] = {}, accoB[4] = {};
  unsigned char* myP = &sP[w][0];
  const int xr = (l15 & 7) << 4;
  float* SpA = scores + ((size_t)bh * 2048 + qtA * 64) * 2048;
  float* SpB = scores + ((size_t)bh * 2048 + qtB * 64) * 2048;

  for (int n = 0; n < NB; n++) {
    if (n + 1 < NB) { stageK(n + 1, (n + 1) & 1); stageVT(n + 1, (n + 1) & 1); }
    if (n == 0) { WV(4); }
    else if (n + 1 < NB) { if (n - 1 <= qtA) { WV(12); } else { WV(8); } }
    else { if (n - 1 <= qtA) { WV(8); } else { WV(4); } }
    SBAR();
    const unsigned short* kb = sK[n & 1];
    const unsigned short* vt = sVT[n & 1];
    int k0 = n * 64;

    // ---- B half ----
    {
      f32x4 acc[4] = {};
      qk_tile(kb, aqB, acc);
      if (n == NB - 1) {
#pragma unroll
        for (int ct = 0; ct < 4; ct++) {
          int kb0 = k0 + ct * 16 + lg * 4;
#pragma unroll
          for (int j = 0; j < 4; j++)
            acc[ct][j] = (kb0 + j <= qrB) ? __builtin_amdgcn_exp2f(acc[ct][j]) * rinvB : 0.f;
        }
      } else {
#pragma unroll
        for (int ct = 0; ct < 4; ct++)
#pragma unroll
          for (int j = 0; j < 4; j++)
            acc[ct][j] = __builtin_amdgcn_exp2f(acc[ct][j]) * rinvB;
      }
      float* srow = SpB + (size_t)(w * 16 + l15) * 2048 + k0 + lg * 4;
#pragma unroll
      for (int ct = 0; ct < 4; ct++) *(f32x4*)(srow + ct * 16) = acc[ct];
#pragma unroll
      for (int ct = 0; ct < 4; ct++) {
        uint2 pw;
        pw.x = cvt_pk(acc[ct][0], acc[ct][1]);
        pw.y = cvt_pk(acc[ct][2], acc[ct][3]);
        *(uint2*)(myP + l15 * 128 + ((ct * 32 + lg * 8) ^ xr)) = pw;
      }
#pragma unroll
      for (int kk = 0; kk < 2; kk++) {
        bf16x8 ap = *(const bf16x8*)(myP + l15 * 128 + ((kk * 64 + lg * 16) ^ xr));
#pragma unroll
        for (int ct = 0; ct < 4; ct++) {
          int vrow = ct * 16 + l15;
          int cv = (kk * 4 + lg) ^ (vrow & 7);
          bf16x8 bv = *(const bf16x8*)((const char*)vt + vrow * 128 + cv * 16);
          accoB[ct] = mfma16(bv, ap, accoB[ct]);
        }
      }
    }

    // ---- A half (only while active; zeros were stored in pass 1) ----
    if (n <= qtA) {
      f32x4 acc[4] = {};
      qk_tile(kb, aqA, acc);
      if (n == qtA) {
#pragma unroll
        for (int ct = 0; ct < 4; ct++) {
          int kb0 = k0 + ct * 16 + lg * 4;
#pragma unroll
          for (int j = 0; j < 4; j++)
            acc[ct][j] = (kb0 + j <= qrA) ? __builtin_amdgcn_exp2f(acc[ct][j]) * rinvA : 0.f;
        }
      } else {
#pragma unroll
        for (int ct = 0; ct < 4; ct++)
#pragma unroll
          for (int j = 0; j < 4; j++)
            acc[ct][j] = __builtin_amdgcn_exp2f(acc[ct][j]) * rinvA;
      }
      float* srow = SpA + (size_t)(w * 16 + l15) * 2048 + k0 + lg * 4;
#pragma unroll
      for (int ct = 0; ct < 4; ct++) *(f32x4*)(srow + ct * 16) = acc[ct];
#pragma unroll
      for (int ct = 0; ct < 4; ct++) {
        uint2 pw;
        pw.x = cvt_pk(acc[ct][0], acc[ct][1]);
        pw.y = cvt_pk(acc[ct][2], acc[ct][3]);
        *(uint2*)(myP + l15 * 128 + ((ct * 32 + lg * 8) ^ xr)) = pw;
      }
#pragma unroll
      for (int kk = 0; kk < 2; kk++) {
        bf16x8 ap = *(const bf16x8*)(myP + l15 * 128 + ((kk * 64 + lg * 16) ^ xr));
#pragma unroll
        for (int ct = 0; ct < 4; ct++) {
          int vrow = ct * 16 + l15;
          int cv = (kk * 4 + lg) ^ (vrow & 7);
          bf16x8 bv = *(const bf16x8*)((const char*)vt + vrow * 128 + cv * 16);
          accoA[ct] = mfma16(bv, ap, accoA[ct]);
        }
      }
    }
    SBAR();
  }

  // O stores: lane holds O[q=l15][d=ct*16+lg*4+..] -> packed uint2
  {
    int mA = b * 2048 + qtA * 64 + w * 16 + l15;
    int mB = b * 2048 + qtB * 64 + w * 16 + l15;
    unsigned int* oA = (unsigned int*)(attn_bf + (size_t)mA * 1024 + h * 64);
    unsigned int* oB = (unsigned int*)(attn_bf + (size_t)mB * 1024 + h * 64);
#pragma unroll
    for (int ct = 0; ct < 4; ct++) {
      uint2 pa, pb;
      pa.x = cvt_pk(accoA[ct][0], accoA[ct][1]);
      pa.y = cvt_pk(accoA[ct][2], accoA[ct][3]);
      pb.x = cvt_pk(accoB[ct][0], accoB[ct][1]);
      pb.y = cvt_pk(accoB[ct][2], accoB[ct][3]);
      *(uint2*)(oA + (ct * 16 + lg * 4) / 2) = pa;
      *(uint2*)(oB + (ct * 16 + lg * 4) / 2) = pb;
    }
  }
}

// ----------------------------------------------------------------- launch ---
extern "C" void kernel_launch(void* const* d_in, const int* in_sizes, int n_in,
                              void* d_out, int out_size, void* d_ws, size_t ws_size,
                              hipStream_t stream) {
  const float* hidden  = (const float*)d_in[0];
  // d_in[1] = mask: causal by construction; applied analytically.
  const float* scaling = (const float*)d_in[2];
  const float* qkv_w   = (const float*)d_in[3];
  const float* qkv_b   = (const float*)d_in[4];
  const float* o_w     = (const float*)d_in[5];
  const float* o_b     = (const float*)d_in[6];

  float* scores = (float*)d_out;                                 // [2][16][2048][2048]
  float* outp   = (float*)d_out + (size_t)2 * 16 * 2048 * 2048;  // [4096][1024]

  char* ws = (char*)d_ws;
  unsigned short* hidden_bf = (unsigned short*)(ws + 0);          //  8 MB
  unsigned short* qkvw_bf   = (unsigned short*)(ws + 8388608);    //  3 MB
  unsigned short* ow_bf     = (unsigned short*)(ws + 11534336);   //  2 MB
  unsigned short* q_ws      = (unsigned short*)(ws + 13631488);   //  8 MB
  unsigned short* k_ws      = (unsigned short*)(ws + 22020096);   //  2 MB
  unsigned short* v_ws      = (unsigned short*)(ws + 24117248);   //  2 MB
  unsigned short* attn_bf   = (unsigned short*)(ws + 26214400);   //  8 MB
  float* qscale             = (float*)(ws + 34603008);            //  256 B

  convert_kernel<<<512, 256, 0, stream>>>(hidden, qkv_w, o_w, scaling,
                                          hidden_bf, qkvw_bf, ow_bf, qscale);
  gemm_kernel<1><<<dim3(12, 32), 256, 0, stream>>>(hidden_bf, qkvw_bf, qkv_b,
                                                   qscale, q_ws, k_ws, v_ws, nullptr);
  attn_kernel<<<512, 256, 0, stream>>>(q_ws, k_ws, v_ws, scores, attn_bf);
  gemm_kernel<2><<<dim3(8, 32), 256, 0, stream>>>(attn_bf, ow_bf, o_b, nullptr,
                                                  nullptr, nullptr, nullptr, outp);
}

// Round 3
// 219.818 us; speedup vs baseline: 1.2915x; 1.0072x over previous
//
#include <hip/hip_runtime.h>
#include <hip/hip_bf16.h>
#include <cstdint>
#include <cstddef>

typedef __attribute__((ext_vector_type(4))) float f32x4;
typedef __attribute__((ext_vector_type(8))) short bf16x8;

#define DEVI static __device__ __forceinline__

DEVI unsigned short f2bf(float f) {
  union { float f; unsigned int u; } v; v.f = f;
  unsigned int u = v.u;
  unsigned int r = (u + 0x7fffu + ((u >> 16) & 1u)) >> 16;
  return (unsigned short)r;
}

// packed fp32 pair -> bf16x2 in one VALU op (RNE)
DEVI unsigned int cvt_pk(float lo, float hi) {
  unsigned int r;
  asm("v_cvt_pk_bf16_f32 %0, %1, %2" : "=v"(r) : "v"(lo), "v"(hi));
  return r;
}

DEVI f32x4 mfma16(bf16x8 a, bf16x8 b, f32x4 c) {
  return __builtin_amdgcn_mfma_f32_16x16x32_bf16(a, b, c, 0, 0, 0);
}

// global -> LDS direct staging, 16B per lane (wave-uniform LDS base).
#define GLDS(gp, lp) __builtin_amdgcn_global_load_lds(                         \
    (const __attribute__((address_space(1))) void*)(const void*)(gp),          \
    (__attribute__((address_space(3))) void*)(void*)(lp), 16, 0, 0)

#define SBAR() asm volatile("s_barrier" ::: "memory")
#define WV(n) asm volatile("s_waitcnt vmcnt(" #n ")" ::: "memory")
#define FORCE4(x) asm volatile("" : "+v"(x))

// ---------------------------------------------------------------- convert ---
__global__ void convert_kernel(const float* __restrict__ hidden,
                               const float* __restrict__ qkv_w,
                               const float* __restrict__ o_w,
                               const float* __restrict__ scaling,
                               unsigned short* __restrict__ hbf,
                               unsigned short* __restrict__ wbf,
                               unsigned short* __restrict__ obf,
                               float* __restrict__ qscale) {
  int tid = blockIdx.x * blockDim.x + threadIdx.x;
  int nt = gridDim.x * blockDim.x;
  if (tid < 64) {
    float x = scaling[tid];
    float sp = (x > 20.f) ? x : log1pf(__expf(x));
    // (1.442695041/8)*softplus, times log2e so softmax can use exp2 directly.
    qscale[tid] = 0.1803368801243369f * 1.4426950408889634f * sp;
  }
  for (int i = tid; i < 1048576; i += nt) {
    float4 v = ((const float4*)hidden)[i];
    ushort4 o = { f2bf(v.x), f2bf(v.y), f2bf(v.z), f2bf(v.w) };
    ((ushort4*)hbf)[i] = o;
  }
  for (int i = tid; i < 393216; i += nt) {
    float4 v = ((const float4*)qkv_w)[i];
    ushort4 o = { f2bf(v.x), f2bf(v.y), f2bf(v.z), f2bf(v.w) };
    ((ushort4*)wbf)[i] = o;
  }
  for (int i = tid; i < 262144; i += nt) {
    float4 v = ((const float4*)o_w)[i];
    ushort4 o = { f2bf(v.x), f2bf(v.y), f2bf(v.z), f2bf(v.w) };
    ((ushort4*)obf)[i] = o;
  }
}

// ------------------------------------------------------------------- GEMM ---
template <int EPI>
__global__ __launch_bounds__(256, 2) void gemm_kernel(
    const unsigned short* __restrict__ A,
    const unsigned short* __restrict__ Bw,
    const float* __restrict__ bias,
    const float* __restrict__ qscale,
    unsigned short* __restrict__ oq,
    unsigned short* __restrict__ okv,
    unsigned short* __restrict__ ovt,
    float* __restrict__ of) {
  __shared__ __align__(16) unsigned short sA[128 * 64];
  __shared__ __align__(16) unsigned short sB[128 * 64];
  const int t = threadIdx.x, lane = t & 63, w = t >> 6;
  const int l15 = lane & 15, lg = lane >> 4;
  const int m0 = blockIdx.y * 128, n0 = blockIdx.x * 128;
  const int wr = w >> 1, wc = w & 1;

  f32x4 acc[4][4] = {};

  for (int kb = 0; kb < 1024; kb += 64) {
    __syncthreads();
#pragma unroll
    for (int i = 0; i < 4; i++) {
      int idx = i * 256 + w * 64 + lane;
      int row = idx >> 3;
      int cg = (idx & 7) ^ (row & 7);
      GLDS(A + (size_t)(m0 + row) * 1024 + kb + cg * 8, sA + (i * 256 + w * 64) * 8);
      GLDS(Bw + (size_t)(n0 + row) * 1024 + kb + cg * 8, sB + (i * 256 + w * 64) * 8);
    }
    __syncthreads();
    bf16x8 af[4][2], bfr[4][2];
#pragma unroll
    for (int rt = 0; rt < 4; rt++) {
      int row = wr * 64 + rt * 16 + l15;
#pragma unroll
      for (int kk = 0; kk < 2; kk++) {
        int c = (kk * 4 + lg) ^ (row & 7);
        af[rt][kk] = *(const bf16x8*)((const char*)sA + row * 128 + c * 16);
      }
      int rowb = wc * 64 + rt * 16 + l15;
#pragma unroll
      for (int kk = 0; kk < 2; kk++) {
        int c = (kk * 4 + lg) ^ (rowb & 7);
        bfr[rt][kk] = *(const bf16x8*)((const char*)sB + rowb * 128 + c * 16);
      }
    }
#pragma unroll
    for (int kk = 0; kk < 2; kk++)
#pragma unroll
      for (int rt = 0; rt < 4; rt++)
#pragma unroll
        for (int ct = 0; ct < 4; ct++)
          acc[rt][ct] = mfma16(af[rt][kk], bfr[ct][kk], acc[rt][ct]);
  }

#pragma unroll
  for (int rt = 0; rt < 4; rt++) {
#pragma unroll
    for (int ct = 0; ct < 4; ct++) {
      int n = n0 + wc * 64 + ct * 16 + l15;
      float bv = bias[n];
#pragma unroll
      for (int jj = 0; jj < 4; jj++) {
        int m = m0 + wr * 64 + rt * 16 + lg * 4 + jj;
        float v = acc[rt][ct][jj] + bv;
        if (EPI == 1) {
          int b = m >> 11, s = m & 2047;
          if (n < 1024) {  // q: scaled, [b][h][s][d]
            int h = n >> 6, d = n & 63;
            v *= qscale[d];
            oq[(((size_t)(b * 16 + h) * 2048 + s) << 6) + d] = f2bf(v);
          } else if (n < 1280) {  // k: [b][kv][s][d]
            int kv = (n - 1024) >> 6, d = n & 63;
            okv[(((size_t)(b * 4 + kv) * 2048 + s) << 6) + d] = f2bf(v);
          } else {  // v transposed: [b][kv][d][s]
            int kv = (n - 1280) >> 6, d = n & 63;
            ovt[(((size_t)((b * 4 + kv) * 64 + d)) << 11) + s] = f2bf(v);
          }
        } else {
          of[(size_t)m * 1024 + n] = v;
        }
      }
    }
  }
}

// -------------------------------------------------------------- attention ---
// Fused-pair: block = (bh, p) handles q-tiles A=p and B=31-p with ONE K-sweep
// per pass (B's extent covers A's). Swapped-operand MFMA (lane owns a q-row),
// per-lane Q loads, dwordx4 P stores, cvt_pk packing. Zero tiles stored
// in-loop (pass 2) + post-loop strip, exactly as the 217us baseline.
//
// THIS REVISION (single change vs 217us baseline): 4-buffer LDS, 2-deep
// prefetch, ONE barrier per iteration.
//  * Skew proof: barrier at top of iter n ensures all waves finished iter n-1
//    compute before anyone proceeds. Fastest wave at iter n stages buf
//    (n+2)&3; slowest may still read buf (n-1)&3 or n&3 -> distinct mod 4.
//  * vmcnt (per wave, in-order): pass 1 (2 GLDS/iter, no stores): steady
//    younger-than-G_n = G_{n+1}(2)+G_{n+2}(2) -> WV(4); tail WV(2)/WV(0).
//    pass 2 (4 GLDS + 8 stores per iter): younger-than-G_n =
//    S_{n-2}(8)+G_{n+1}(4)+S_{n-1}(8)+G_{n+2}(4) = 24 steady;
//    n=0 -> 8, n=1 -> 16, n=NB-2 -> 20, n=NB-1 -> 16.
//  * Explicit SBAR between passes (pass-2 staging of buf0 vs pass-1 readers).
__global__ __launch_bounds__(256, 2) void attn_kernel(
    const unsigned short* __restrict__ q_ws,
    const unsigned short* __restrict__ k_ws,
    const unsigned short* __restrict__ v_ws,
    float* __restrict__ scores,
    unsigned short* __restrict__ attn_bf) {
  __shared__ __align__(16) unsigned short sK[4][4096];
  __shared__ __align__(16) unsigned short sVT[4][4096];
  __shared__ __align__(16) unsigned char sP[4][2048];

  const int t = threadIdx.x, lane = t & 63, w = t >> 6;
  const int l15 = lane & 15, lg = lane >> 4;
  int bid = blockIdx.x;
  int bh = bid & 31;            // b*16+h
  int p = bid >> 5;             // 0..15
  int b = bh >> 4, h = bh & 15, kv = h >> 2;
  const int qtA = p, qtB = 31 - p;
  const int NB = qtB + 1;       // 17..32 k-tiles (covers A's p+1)

  const unsigned short* Kp = k_ws + ((size_t)(b * 4 + kv) * 2048) * 64;
  const unsigned short* Vp = v_ws + ((size_t)(b * 4 + kv) * 64) * 2048;  // [d][s]
  const int qrA = qtA * 64 + w * 16 + l15;   // this lane's A q-row
  const int qrB = qtB * 64 + w * 16 + l15;   // this lane's B q-row

  // per-lane Q fragments (compiler-tracked; FORCE4 drains them before staging)
  bf16x8 aqA[2], aqB[2];
  {
    const unsigned short* qa = q_ws + ((size_t)bh * 2048 + qrA) * 64;
    const unsigned short* qb = q_ws + ((size_t)bh * 2048 + qrB) * 64;
    aqA[0] = *(const bf16x8*)(qa + lg * 8);
    aqA[1] = *(const bf16x8*)(qa + 32 + lg * 8);
    aqB[0] = *(const bf16x8*)(qb + lg * 8);
    aqB[1] = *(const bf16x8*)(qb + 32 + lg * 8);
    FORCE4(*(f32x4*)&aqA[0]); FORCE4(*(f32x4*)&aqA[1]);
    FORCE4(*(f32x4*)&aqB[0]); FORCE4(*(f32x4*)&aqB[1]);
  }

  auto stageK = [&](int kt, int bufi) {  // 2 GLDS per wave
#pragma unroll
    for (int i = 0; i < 2; i++) {
      int idx = i * 256 + w * 64 + lane;
      int row = idx >> 3;
      int cg = (idx & 7) ^ (row & 7);
      GLDS(Kp + (size_t)(kt * 64 + row) * 64 + cg * 8, sK[bufi] + (i * 256 + w * 64) * 8);
    }
  };
  auto stageVT = [&](int kt, int bufi) {  // 2 GLDS per wave
#pragma unroll
    for (int i = 0; i < 2; i++) {
      int idx = i * 256 + w * 64 + lane;
      int row = idx >> 3;
      int cg = (idx & 7) ^ (row & 7);
      GLDS(Vp + (size_t)row * 2048 + kt * 64 + cg * 8, sVT[bufi] + (i * 256 + w * 64) * 8);
    }
  };
  // swapped QK^T: K rows as A, Q as B -> acc[ct][j] = S[q=l15][k0+ct*16+lg*4+j]
  auto qk_tile = [&](const unsigned short* kb, const bf16x8(&aq)[2], f32x4(&acc)[4]) {
#pragma unroll
    for (int ct = 0; ct < 4; ct++) {
      int row = ct * 16 + l15;
#pragma unroll
      for (int kk = 0; kk < 2; kk++) {
        int c = (kk * 4 + lg) ^ (row & 7);
        bf16x8 ak = *(const bf16x8*)((const char*)kb + row * 128 + c * 16);
        acc[ct] = mfma16(ak, aq[kk], acc[ct]);
      }
    }
  };

  // ---- pass 1: rowsums for BOTH halves, one K sweep, 2-deep prefetch ----
  stageK(0, 0);
  stageK(1, 1);
  float rsA = 0.f, rsB = 0.f;
  for (int n = 0; n < NB; n++) {
    if (n + 2 < NB) { stageK(n + 2, (n + 2) & 3); WV(4); }
    else if (n + 1 < NB) { WV(2); }
    else { WV(0); }
    SBAR();
    const unsigned short* kb = sK[n & 3];
    {
      f32x4 acc[4] = {};
      qk_tile(kb, aqB, acc);
      if (n < NB - 1) {
#pragma unroll
        for (int ct = 0; ct < 4; ct++)
#pragma unroll
          for (int j = 0; j < 4; j++) rsB += __builtin_amdgcn_exp2f(acc[ct][j]);
      } else {
#pragma unroll
        for (int ct = 0; ct < 4; ct++) {
          int kb0 = n * 64 + ct * 16 + lg * 4;
#pragma unroll
          for (int j = 0; j < 4; j++)
            rsB += (kb0 + j <= qrB) ? __builtin_amdgcn_exp2f(acc[ct][j]) : 0.f;
        }
      }
    }
    if (n <= qtA) {
      f32x4 acc[4] = {};
      qk_tile(kb, aqA, acc);
      if (n < qtA) {
#pragma unroll
        for (int ct = 0; ct < 4; ct++)
#pragma unroll
          for (int j = 0; j < 4; j++) rsA += __builtin_amdgcn_exp2f(acc[ct][j]);
      } else {
#pragma unroll
        for (int ct = 0; ct < 4; ct++) {
          int kb0 = n * 64 + ct * 16 + lg * 4;
#pragma unroll
          for (int j = 0; j < 4; j++)
            rsA += (kb0 + j <= qrA) ? __builtin_amdgcn_exp2f(acc[ct][j]) : 0.f;
        }
      }
    }
    // no bottom barrier: 4-buffer skew proof in header comment
  }
  rsA += __shfl_xor(rsA, 16); rsA += __shfl_xor(rsA, 32);
  rsB += __shfl_xor(rsB, 16); rsB += __shfl_xor(rsB, 32);
  float rinvA = 1.0f / rsA, rinvB = 1.0f / rsB;

  SBAR();  // pass-1 readers done before pass-2 staging reuses buffers

  // ---- pass 2: P stores + in-loop zeros + PV, 2-deep prefetch ----
  stageK(0, 0); stageVT(0, 0);
  stageK(1, 1); stageVT(1, 1);
  f32x4 accoA[4] = {}, accoB[4] = {};
  unsigned char* myP = &sP[w][0];
  const int xr = (l15 & 7) << 4;
  float* SpA = scores + ((size_t)bh * 2048 + qtA * 64) * 2048;
  float* SpB = scores + ((size_t)bh * 2048 + qtB * 64) * 2048;

  for (int n = 0; n < NB; n++) {
    if (n + 2 < NB) { stageK(n + 2, (n + 2) & 3); stageVT(n + 2, (n + 2) & 3); }
    if (n == 0) { WV(8); }
    else if (n == 1) { WV(16); }
    else if (n + 2 < NB) { WV(24); }
    else if (n + 1 < NB) { WV(20); }
    else { WV(16); }
    SBAR();
    const unsigned short* kb = sK[n & 3];
    const unsigned short* vt = sVT[n & 3];
    int k0 = n * 64;

    // ---- B half ----
    {
      f32x4 acc[4] = {};
      qk_tile(kb, aqB, acc);
      if (n == NB - 1) {
#pragma unroll
        for (int ct = 0; ct < 4; ct++) {
          int kb0 = k0 + ct * 16 + lg * 4;
#pragma unroll
          for (int j = 0; j < 4; j++)
            acc[ct][j] = (kb0 + j <= qrB) ? __builtin_amdgcn_exp2f(acc[ct][j]) * rinvB : 0.f;
        }
      } else {
#pragma unroll
        for (int ct = 0; ct < 4; ct++)
#pragma unroll
          for (int j = 0; j < 4; j++)
            acc[ct][j] = __builtin_amdgcn_exp2f(acc[ct][j]) * rinvB;
      }
      float* srow = SpB + (size_t)(w * 16 + l15) * 2048 + k0 + lg * 4;
#pragma unroll
      for (int ct = 0; ct < 4; ct++) *(f32x4*)(srow + ct * 16) = acc[ct];
#pragma unroll
      for (int ct = 0; ct < 4; ct++) {
        uint2 pw;
        pw.x = cvt_pk(acc[ct][0], acc[ct][1]);
        pw.y = cvt_pk(acc[ct][2], acc[ct][3]);
        *(uint2*)(myP + l15 * 128 + ((ct * 32 + lg * 8) ^ xr)) = pw;
      }
#pragma unroll
      for (int kk = 0; kk < 2; kk++) {
        bf16x8 ap = *(const bf16x8*)(myP + l15 * 128 + ((kk * 64 + lg * 16) ^ xr));
#pragma unroll
        for (int ct = 0; ct < 4; ct++) {
          int vrow = ct * 16 + l15;
          int cv = (kk * 4 + lg) ^ (vrow & 7);
          bf16x8 bv = *(const bf16x8*)((const char*)vt + vrow * 128 + cv * 16);
          accoB[ct] = mfma16(bv, ap, accoB[ct]);
        }
      }
    }

    // ---- A half (or its in-loop zero tile: keeps 8 stores/iter) ----
    if (n <= qtA) {
      f32x4 acc[4] = {};
      qk_tile(kb, aqA, acc);
      if (n == qtA) {
#pragma unroll
        for (int ct = 0; ct < 4; ct++) {
          int kb0 = k0 + ct * 16 + lg * 4;
#pragma unroll
          for (int j = 0; j < 4; j++)
            acc[ct][j] = (kb0 + j <= qrA) ? __builtin_amdgcn_exp2f(acc[ct][j]) * rinvA : 0.f;
        }
      } else {
#pragma unroll
        for (int ct = 0; ct < 4; ct++)
#pragma unroll
          for (int j = 0; j < 4; j++)
            acc[ct][j] = __builtin_amdgcn_exp2f(acc[ct][j]) * rinvA;
      }
      float* srow = SpA + (size_t)(w * 16 + l15) * 2048 + k0 + lg * 4;
#pragma unroll
      for (int ct = 0; ct < 4; ct++) *(f32x4*)(srow + ct * 16) = acc[ct];
#pragma unroll
      for (int ct = 0; ct < 4; ct++) {
        uint2 pw;
        pw.x = cvt_pk(acc[ct][0], acc[ct][1]);
        pw.y = cvt_pk(acc[ct][2], acc[ct][3]);
        *(uint2*)(myP + l15 * 128 + ((ct * 32 + lg * 8) ^ xr)) = pw;
      }
#pragma unroll
      for (int kk = 0; kk < 2; kk++) {
        bf16x8 ap = *(const bf16x8*)(myP + l15 * 128 + ((kk * 64 + lg * 16) ^ xr));
#pragma unroll
        for (int ct = 0; ct < 4; ct++) {
          int vrow = ct * 16 + l15;
          int cv = (kk * 4 + lg) ^ (vrow & 7);
          bf16x8 bv = *(const bf16x8*)((const char*)vt + vrow * 128 + cv * 16);
          accoA[ct] = mfma16(bv, ap, accoA[ct]);
        }
      }
    } else {
      f32x4 z = {0.f, 0.f, 0.f, 0.f};
      float* srow = SpA + (size_t)(w * 16 + l15) * 2048 + k0 + lg * 4;
#pragma unroll
      for (int ct = 0; ct < 4; ct++) *(f32x4*)(srow + ct * 16) = z;
    }
    // no bottom barrier: 4-buffer skew proof in header comment
  }

  // O stores: lane holds O[q=l15][d=ct*16+lg*4+..] -> packed uint2
  {
    int mA = b * 2048 + qtA * 64 + w * 16 + l15;
    int mB = b * 2048 + qtB * 64 + w * 16 + l15;
    unsigned int* oA = (unsigned int*)(attn_bf + (size_t)mA * 1024 + h * 64);
    unsigned int* oB = (unsigned int*)(attn_bf + (size_t)mB * 1024 + h * 64);
#pragma unroll
    for (int ct = 0; ct < 4; ct++) {
      uint2 pa, pb;
      pa.x = cvt_pk(accoA[ct][0], accoA[ct][1]);
      pa.y = cvt_pk(accoA[ct][2], accoA[ct][3]);
      pb.x = cvt_pk(accoB[ct][0], accoB[ct][1]);
      pb.y = cvt_pk(accoB[ct][2], accoB[ct][3]);
      *(uint2*)(oA + (ct * 16 + lg * 4) / 2) = pa;
      *(uint2*)(oB + (ct * 16 + lg * 4) / 2) = pb;
    }
  }

  // residual zero strip: cols [NB*64, 2048) for this lane's A and B rows
  int zbase = NB * 64;
  if (zbase < 2048) {
    f32x4 z = {0.f, 0.f, 0.f, 0.f};
    float* ra = scores + ((size_t)bh * 2048 + qrA) * 2048;
    float* rb = scores + ((size_t)bh * 2048 + qrB) * 2048;
    for (int c = zbase + lg * 4; c < 2048; c += 16) {
      *(f32x4*)(ra + c) = z;
      *(f32x4*)(rb + c) = z;
    }
  }
}

// ----------------------------------------------------------------- launch ---
extern "C" void kernel_launch(void* const* d_in, const int* in_sizes, int n_in,
                              void* d_out, int out_size, void* d_ws, size_t ws_size,
                              hipStream_t stream) {
  const float* hidden  = (const float*)d_in[0];
  // d_in[1] = mask: causal by construction; applied analytically.
  const float* scaling = (const float*)d_in[2];
  const float* qkv_w   = (const float*)d_in[3];
  const float* qkv_b   = (const float*)d_in[4];
  const float* o_w     = (const float*)d_in[5];
  const float* o_b     = (const float*)d_in[6];

  float* scores = (float*)d_out;                                 // [2][16][2048][2048]
  float* outp   = (float*)d_out + (size_t)2 * 16 * 2048 * 2048;  // [4096][1024]

  char* ws = (char*)d_ws;
  unsigned short* hidden_bf = (unsigned short*)(ws + 0);          //  8 MB
  unsigned short* qkvw_bf   = (unsigned short*)(ws + 8388608);    //  3 MB
  unsigned short* ow_bf     = (unsigned short*)(ws + 11534336);   //  2 MB
  unsigned short* q_ws      = (unsigned short*)(ws + 13631488);   //  8 MB
  unsigned short* k_ws      = (unsigned short*)(ws + 22020096);   //  2 MB
  unsigned short* v_ws      = (unsigned short*)(ws + 24117248);   //  2 MB
  unsigned short* attn_bf   = (unsigned short*)(ws + 26214400);   //  8 MB
  float* qscale             = (float*)(ws + 34603008);            //  256 B

  convert_kernel<<<512, 256, 0, stream>>>(hidden, qkv_w, o_w, scaling,
                                          hidden_bf, qkvw_bf, ow_bf, qscale);
  gemm_kernel<1><<<dim3(12, 32), 256, 0, stream>>>(hidden_bf, qkvw_bf, qkv_b,
                                                   qscale, q_ws, k_ws, v_ws, nullptr);
  attn_kernel<<<512, 256, 0, stream>>>(q_ws, k_ws, v_ws, scores, attn_bf);
  gemm_kernel<2><<<dim3(8, 32), 256, 0, stream>>>(attn_bf, ow_bf, o_b, nullptr,
                                                  nullptr, nullptr, nullptr, outp);
}

// Round 4
// 215.274 us; speedup vs baseline: 1.3187x; 1.0211x over previous
//
#include <hip/hip_runtime.h>
#include <hip/hip_bf16.h>
#include <cstdint>
#include <cstddef>

typedef __attribute__((ext_vector_type(4))) float f32x4;
typedef __attribute__((ext_vector_type(8))) short bf16x8;

#define DEVI static __device__ __forceinline__

DEVI unsigned short f2bf(float f) {
  union { float f; unsigned int u; } v; v.f = f;
  unsigned int u = v.u;
  unsigned int r = (u + 0x7fffu + ((u >> 16) & 1u)) >> 16;
  return (unsigned short)r;
}

// packed fp32 pair -> bf16x2 in one VALU op (RNE)
DEVI unsigned int cvt_pk(float lo, float hi) {
  unsigned int r;
  asm("v_cvt_pk_bf16_f32 %0, %1, %2" : "=v"(r) : "v"(lo), "v"(hi));
  return r;
}

DEVI f32x4 mfma16(bf16x8 a, bf16x8 b, f32x4 c) {
  return __builtin_amdgcn_mfma_f32_16x16x32_bf16(a, b, c, 0, 0, 0);
}

// global -> LDS direct staging, 16B per lane (wave-uniform LDS base).
#define GLDS(gp, lp) __builtin_amdgcn_global_load_lds(                         \
    (const __attribute__((address_space(1))) void*)(const void*)(gp),          \
    (__attribute__((address_space(3))) void*)(void*)(lp), 16, 0, 0)

#define SBAR() asm volatile("s_barrier" ::: "memory")
#define WV(n) asm volatile("s_waitcnt vmcnt(" #n ")" ::: "memory")
#define FORCE4(x) asm volatile("" : "+v"(x))

// ---------------------------------------------------------------- convert ---
__global__ void convert_kernel(const float* __restrict__ hidden,
                               const float* __restrict__ qkv_w,
                               const float* __restrict__ o_w,
                               const float* __restrict__ scaling,
                               unsigned short* __restrict__ hbf,
                               unsigned short* __restrict__ wbf,
                               unsigned short* __restrict__ obf,
                               float* __restrict__ qscale) {
  int tid = blockIdx.x * blockDim.x + threadIdx.x;
  int nt = gridDim.x * blockDim.x;
  if (tid < 64) {
    float x = scaling[tid];
    float sp = (x > 20.f) ? x : log1pf(__expf(x));
    // (1.442695041/8)*softplus, times log2e so softmax can use exp2 directly.
    qscale[tid] = 0.1803368801243369f * 1.4426950408889634f * sp;
  }
  for (int i = tid; i < 1048576; i += nt) {
    float4 v = ((const float4*)hidden)[i];
    ushort4 o = { f2bf(v.x), f2bf(v.y), f2bf(v.z), f2bf(v.w) };
    ((ushort4*)hbf)[i] = o;
  }
  for (int i = tid; i < 393216; i += nt) {
    float4 v = ((const float4*)qkv_w)[i];
    ushort4 o = { f2bf(v.x), f2bf(v.y), f2bf(v.z), f2bf(v.w) };
    ((ushort4*)wbf)[i] = o;
  }
  for (int i = tid; i < 262144; i += nt) {
    float4 v = ((const float4*)o_w)[i];
    ushort4 o = { f2bf(v.x), f2bf(v.y), f2bf(v.z), f2bf(v.w) };
    ((ushort4*)obf)[i] = o;
  }
}

// ------------------------------------------------------ GEMM 1 (qkv proj) ---
__global__ __launch_bounds__(256, 2) void gemm_kernel(
    const unsigned short* __restrict__ A,
    const unsigned short* __restrict__ Bw,
    const float* __restrict__ bias,
    const float* __restrict__ qscale,
    unsigned short* __restrict__ oq,
    unsigned short* __restrict__ okv,
    unsigned short* __restrict__ ovt) {
  __shared__ __align__(16) unsigned short sA[128 * 64];
  __shared__ __align__(16) unsigned short sB[128 * 64];
  const int t = threadIdx.x, lane = t & 63, w = t >> 6;
  const int l15 = lane & 15, lg = lane >> 4;
  const int m0 = blockIdx.y * 128, n0 = blockIdx.x * 128;
  const int wr = w >> 1, wc = w & 1;

  f32x4 acc[4][4] = {};

  for (int kb = 0; kb < 1024; kb += 64) {
    __syncthreads();
#pragma unroll
    for (int i = 0; i < 4; i++) {
      int idx = i * 256 + w * 64 + lane;
      int row = idx >> 3;
      int cg = (idx & 7) ^ (row & 7);
      GLDS(A + (size_t)(m0 + row) * 1024 + kb + cg * 8, sA + (i * 256 + w * 64) * 8);
      GLDS(Bw + (size_t)(n0 + row) * 1024 + kb + cg * 8, sB + (i * 256 + w * 64) * 8);
    }
    __syncthreads();
    bf16x8 af[4][2], bfr[4][2];
#pragma unroll
    for (int rt = 0; rt < 4; rt++) {
      int row = wr * 64 + rt * 16 + l15;
#pragma unroll
      for (int kk = 0; kk < 2; kk++) {
        int c = (kk * 4 + lg) ^ (row & 7);
        af[rt][kk] = *(const bf16x8*)((const char*)sA + row * 128 + c * 16);
      }
      int rowb = wc * 64 + rt * 16 + l15;
#pragma unroll
      for (int kk = 0; kk < 2; kk++) {
        int c = (kk * 4 + lg) ^ (rowb & 7);
        bfr[rt][kk] = *(const bf16x8*)((const char*)sB + rowb * 128 + c * 16);
      }
    }
#pragma unroll
    for (int kk = 0; kk < 2; kk++)
#pragma unroll
      for (int rt = 0; rt < 4; rt++)
#pragma unroll
        for (int ct = 0; ct < 4; ct++)
          acc[rt][ct] = mfma16(af[rt][kk], bfr[ct][kk], acc[rt][ct]);
  }

#pragma unroll
  for (int rt = 0; rt < 4; rt++) {
#pragma unroll
    for (int ct = 0; ct < 4; ct++) {
      int n = n0 + wc * 64 + ct * 16 + l15;
      float bv = bias[n];
#pragma unroll
      for (int jj = 0; jj < 4; jj++) {
        int m = m0 + wr * 64 + rt * 16 + lg * 4 + jj;
        float v = acc[rt][ct][jj] + bv;
        int b = m >> 11, s = m & 2047;
        if (n < 1024) {  // q: scaled, [b][h][s][d]
          int h = n >> 6, d = n & 63;
          v *= qscale[d];
          oq[(((size_t)(b * 16 + h) * 2048 + s) << 6) + d] = f2bf(v);
        } else if (n < 1280) {  // k: [b][kv][s][d]
          int kv = (n - 1024) >> 6, d = n & 63;
          okv[(((size_t)(b * 4 + kv) * 2048 + s) << 6) + d] = f2bf(v);
        } else {  // v transposed: [b][kv][d][s]
          int kv = (n - 1280) >> 6, d = n & 63;
          ovt[(((size_t)((b * 4 + kv) * 64 + d)) << 11) + s] = f2bf(v);
        }
      }
    }
  }
}

// ----------------------------------------------------- GEMM 2 (out proj) ----
// 64x128 tile -> grid (8,64) = 512 blocks = 2 blocks/CU (was 256 = 1/CU with
// only 1 wave/SIMD: every MFMA/lgkm dependency exposed). 4 waves, each owns a
// 32x64 sub-tile: acc[2][4].
__global__ __launch_bounds__(256, 2) void gemm2_kernel(
    const unsigned short* __restrict__ A,    // [4096][1024] bf16
    const unsigned short* __restrict__ Bw,   // [1024][1024] bf16 (o_w)
    const float* __restrict__ bias,
    float* __restrict__ of) {
  __shared__ __align__(16) unsigned short sA[64 * 64];
  __shared__ __align__(16) unsigned short sB[128 * 64];
  const int t = threadIdx.x, lane = t & 63, w = t >> 6;
  const int l15 = lane & 15, lg = lane >> 4;
  const int m0 = blockIdx.y * 64, n0 = blockIdx.x * 128;
  const int wr = w >> 1, wc = w & 1;  // 2x2 wave grid over 64x128

  f32x4 acc[2][4] = {};

  for (int kb = 0; kb < 1024; kb += 64) {
    __syncthreads();
    // stage A: 64 rows x 64 cols = 512 16B-chunks -> 2 per thread
#pragma unroll
    for (int i = 0; i < 2; i++) {
      int idx = i * 256 + w * 64 + lane;
      int row = idx >> 3;
      int cg = (idx & 7) ^ (row & 7);
      GLDS(A + (size_t)(m0 + row) * 1024 + kb + cg * 8, sA + (i * 256 + w * 64) * 8);
    }
    // stage B: 128 rows -> 4 per thread
#pragma unroll
    for (int i = 0; i < 4; i++) {
      int idx = i * 256 + w * 64 + lane;
      int row = idx >> 3;
      int cg = (idx & 7) ^ (row & 7);
      GLDS(Bw + (size_t)(n0 + row) * 1024 + kb + cg * 8, sB + (i * 256 + w * 64) * 8);
    }
    __syncthreads();
    bf16x8 af[2][2], bfr[4][2];
#pragma unroll
    for (int rt = 0; rt < 2; rt++) {
      int row = wr * 32 + rt * 16 + l15;
#pragma unroll
      for (int kk = 0; kk < 2; kk++) {
        int c = (kk * 4 + lg) ^ (row & 7);
        af[rt][kk] = *(const bf16x8*)((const char*)sA + row * 128 + c * 16);
      }
    }
#pragma unroll
    for (int ct = 0; ct < 4; ct++) {
      int rowb = wc * 64 + ct * 16 + l15;
#pragma unroll
      for (int kk = 0; kk < 2; kk++) {
        int c = (kk * 4 + lg) ^ (rowb & 7);
        bfr[ct][kk] = *(const bf16x8*)((const char*)sB + rowb * 128 + c * 16);
      }
    }
#pragma unroll
    for (int kk = 0; kk < 2; kk++)
#pragma unroll
      for (int rt = 0; rt < 2; rt++)
#pragma unroll
        for (int ct = 0; ct < 4; ct++)
          acc[rt][ct] = mfma16(af[rt][kk], bfr[ct][kk], acc[rt][ct]);
  }

#pragma unroll
  for (int rt = 0; rt < 2; rt++) {
#pragma unroll
    for (int ct = 0; ct < 4; ct++) {
      int n = n0 + wc * 64 + ct * 16 + l15;
      float bv = bias[n];
#pragma unroll
      for (int jj = 0; jj < 4; jj++) {
        int m = m0 + wr * 32 + rt * 16 + lg * 4 + jj;
        of[(size_t)m * 1024 + n] = acc[rt][ct][jj] + bv;
      }
    }
  }
}

// -------------------------------------------------------------- attention ---
// Fused-pair: block = (bh, p) handles q-tiles A=p and B=31-p with ONE K-sweep
// per pass (B's extent covers A's). Swapped-operand MFMA (lane owns a q-row),
// per-lane Q loads, dwordx4 P stores, cvt_pk packing. Zero tiles stored
// in-loop (pass 2) + post-loop strip. 4-buffer LDS, 2-deep prefetch, one
// barrier per iteration (round-2 structure; skew proof below).
//
// THIS REVISION: CU load-balance remap of p. Block cost = NB = 32-p iters
// (17..32). With 512 blocks on 512 resident slots, bid and bid+256 co-reside
// on a CU (round-robin XCD fill). Old p=bid>>5 paired (p, p+8): CU load
// 56-2p, max 56 vs balanced 49 -> slowest-CU pacing. New mapping pairs p and
// 15-p so EVERY CU sums to 49: bid<256 -> p=bid>>5 (0..7); bid>=256 ->
// p=23-(bid>>5) (15..8). Pure work permutation, correctness-neutral.
//
//  * Skew proof: barrier at top of iter n ensures all waves finished iter n-1
//    compute before anyone proceeds. Fastest wave at iter n stages buf
//    (n+2)&3; slowest may still read buf (n-1)&3 or n&3 -> distinct mod 4.
//  * vmcnt (per wave, in-order): pass 1 (2 GLDS/iter, no stores): steady
//    younger-than-G_n = G_{n+1}(2)+G_{n+2}(2) -> WV(4); tail WV(2)/WV(0).
//    pass 2 (4 GLDS + 8 stores per iter): younger-than-G_n =
//    S_{n-2}(8)+G_{n+1}(4)+S_{n-1}(8)+G_{n+2}(4) = 24 steady;
//    n=0 -> 8, n=1 -> 16, n=NB-2 -> 20, n=NB-1 -> 16.
//  * Explicit SBAR between passes (pass-2 staging of buf0 vs pass-1 readers).
__global__ __launch_bounds__(256, 2) void attn_kernel(
    const unsigned short* __restrict__ q_ws,
    const unsigned short* __restrict__ k_ws,
    const unsigned short* __restrict__ v_ws,
    float* __restrict__ scores,
    unsigned short* __restrict__ attn_bf) {
  __shared__ __align__(16) unsigned short sK[4][4096];
  __shared__ __align__(16) unsigned short sVT[4][4096];
  __shared__ __align__(16) unsigned char sP[4][2048];

  const int t = threadIdx.x, lane = t & 63, w = t >> 6;
  const int l15 = lane & 15, lg = lane >> 4;
  int bid = blockIdx.x;
  int bh = bid & 31;            // b*16+h
  int pr = bid >> 5;            // 0..15
  int p = (bid < 256) ? pr : (23 - pr);  // balance: bid & bid+256 -> p & 15-p
  int b = bh >> 4, h = bh & 15, kv = h >> 2;
  const int qtA = p, qtB = 31 - p;
  const int NB = qtB + 1;       // 17..32 k-tiles (covers A's p+1)

  const unsigned short* Kp = k_ws + ((size_t)(b * 4 + kv) * 2048) * 64;
  const unsigned short* Vp = v_ws + ((size_t)(b * 4 + kv) * 64) * 2048;  // [d][s]
  const int qrA = qtA * 64 + w * 16 + l15;   // this lane's A q-row
  const int qrB = qtB * 64 + w * 16 + l15;   // this lane's B q-row

  // per-lane Q fragments (compiler-tracked; FORCE4 drains them before staging)
  bf16x8 aqA[2], aqB[2];
  {
    const unsigned short* qa = q_ws + ((size_t)bh * 2048 + qrA) * 64;
    const unsigned short* qb = q_ws + ((size_t)bh * 2048 + qrB) * 64;
    aqA[0] = *(const bf16x8*)(qa + lg * 8);
    aqA[1] = *(const bf16x8*)(qa + 32 + lg * 8);
    aqB[0] = *(const bf16x8*)(qb + lg * 8);
    aqB[1] = *(const bf16x8*)(qb + 32 + lg * 8);
    FORCE4(*(f32x4*)&aqA[0]); FORCE4(*(f32x4*)&aqA[1]);
    FORCE4(*(f32x4*)&aqB[0]); FORCE4(*(f32x4*)&aqB[1]);
  }

  auto stageK = [&](int kt, int bufi) {  // 2 GLDS per wave
#pragma unroll
    for (int i = 0; i < 2; i++) {
      int idx = i * 256 + w * 64 + lane;
      int row = idx >> 3;
      int cg = (idx & 7) ^ (row & 7);
      GLDS(Kp + (size_t)(kt * 64 + row) * 64 + cg * 8, sK[bufi] + (i * 256 + w * 64) * 8);
    }
  };
  auto stageVT = [&](int kt, int bufi) {  // 2 GLDS per wave
#pragma unroll
    for (int i = 0; i < 2; i++) {
      int idx = i * 256 + w * 64 + lane;
      int row = idx >> 3;
      int cg = (idx & 7) ^ (row & 7);
      GLDS(Vp + (size_t)row * 2048 + kt * 64 + cg * 8, sVT[bufi] + (i * 256 + w * 64) * 8);
    }
  };
  // swapped QK^T: K rows as A, Q as B -> acc[ct][j] = S[q=l15][k0+ct*16+lg*4+j]
  auto qk_tile = [&](const unsigned short* kb, const bf16x8(&aq)[2], f32x4(&acc)[4]) {
#pragma unroll
    for (int ct = 0; ct < 4; ct++) {
      int row = ct * 16 + l15;
#pragma unroll
      for (int kk = 0; kk < 2; kk++) {
        int c = (kk * 4 + lg) ^ (row & 7);
        bf16x8 ak = *(const bf16x8*)((const char*)kb + row * 128 + c * 16);
        acc[ct] = mfma16(ak, aq[kk], acc[ct]);
      }
    }
  };

  // ---- pass 1: rowsums for BOTH halves, one K sweep, 2-deep prefetch ----
  stageK(0, 0);
  stageK(1, 1);
  float rsA = 0.f, rsB = 0.f;
  for (int n = 0; n < NB; n++) {
    if (n + 2 < NB) { stageK(n + 2, (n + 2) & 3); WV(4); }
    else if (n + 1 < NB) { WV(2); }
    else { WV(0); }
    SBAR();
    const unsigned short* kb = sK[n & 3];
    {
      f32x4 acc[4] = {};
      qk_tile(kb, aqB, acc);
      if (n < NB - 1) {
#pragma unroll
        for (int ct = 0; ct < 4; ct++)
#pragma unroll
          for (int j = 0; j < 4; j++) rsB += __builtin_amdgcn_exp2f(acc[ct][j]);
      } else {
#pragma unroll
        for (int ct = 0; ct < 4; ct++) {
          int kb0 = n * 64 + ct * 16 + lg * 4;
#pragma unroll
          for (int j = 0; j < 4; j++)
            rsB += (kb0 + j <= qrB) ? __builtin_amdgcn_exp2f(acc[ct][j]) : 0.f;
        }
      }
    }
    if (n <= qtA) {
      f32x4 acc[4] = {};
      qk_tile(kb, aqA, acc);
      if (n < qtA) {
#pragma unroll
        for (int ct = 0; ct < 4; ct++)
#pragma unroll
          for (int j = 0; j < 4; j++) rsA += __builtin_amdgcn_exp2f(acc[ct][j]);
      } else {
#pragma unroll
        for (int ct = 0; ct < 4; ct++) {
          int kb0 = n * 64 + ct * 16 + lg * 4;
#pragma unroll
          for (int j = 0; j < 4; j++)
            rsA += (kb0 + j <= qrA) ? __builtin_amdgcn_exp2f(acc[ct][j]) : 0.f;
        }
      }
    }
    // no bottom barrier: 4-buffer skew proof in header comment
  }
  rsA += __shfl_xor(rsA, 16); rsA += __shfl_xor(rsA, 32);
  rsB += __shfl_xor(rsB, 16); rsB += __shfl_xor(rsB, 32);
  float rinvA = 1.0f / rsA, rinvB = 1.0f / rsB;

  SBAR();  // pass-1 readers done before pass-2 staging reuses buffers

  // ---- pass 2: P stores + in-loop zeros + PV, 2-deep prefetch ----
  stageK(0, 0); stageVT(0, 0);
  stageK(1, 1); stageVT(1, 1);
  f32x4 accoA[4] = {}, accoB[4] = {};
  unsigned char* myP = &sP[w][0];
  const int xr = (l15 & 7) << 4;
  float* SpA = scores + ((size_t)bh * 2048 + qtA * 64) * 2048;
  float* SpB = scores + ((size_t)bh * 2048 + qtB * 64) * 2048;

  for (int n = 0; n < NB; n++) {
    if (n + 2 < NB) { stageK(n + 2, (n + 2) & 3); stageVT(n + 2, (n + 2) & 3); }
    if (n == 0) { WV(8); }
    else if (n == 1) { WV(16); }
    else if (n + 2 < NB) { WV(24); }
    else if (n + 1 < NB) { WV(20); }
    else { WV(16); }
    SBAR();
    const unsigned short* kb = sK[n & 3];
    const unsigned short* vt = sVT[n & 3];
    int k0 = n * 64;

    // ---- B half ----
    {
      f32x4 acc[4] = {};
      qk_tile(kb, aqB, acc);
      if (n == NB - 1) {
#pragma unroll
        for (int ct = 0; ct < 4; ct++) {
          int kb0 = k0 + ct * 16 + lg * 4;
#pragma unroll
          for (int j = 0; j < 4; j++)
            acc[ct][j] = (kb0 + j <= qrB) ? __builtin_amdgcn_exp2f(acc[ct][j]) * rinvB : 0.f;
        }
      } else {
#pragma unroll
        for (int ct = 0; ct < 4; ct++)
#pragma unroll
          for (int j = 0; j < 4; j++)
            acc[ct][j] = __builtin_amdgcn_exp2f(acc[ct][j]) * rinvB;
      }
      float* srow = SpB + (size_t)(w * 16 + l15) * 2048 + k0 + lg * 4;
#pragma unroll
      for (int ct = 0; ct < 4; ct++) *(f32x4*)(srow + ct * 16) = acc[ct];
#pragma unroll
      for (int ct = 0; ct < 4; ct++) {
        uint2 pw;
        pw.x = cvt_pk(acc[ct][0], acc[ct][1]);
        pw.y = cvt_pk(acc[ct][2], acc[ct][3]);
        *(uint2*)(myP + l15 * 128 + ((ct * 32 + lg * 8) ^ xr)) = pw;
      }
#pragma unroll
      for (int kk = 0; kk < 2; kk++) {
        bf16x8 ap = *(const bf16x8*)(myP + l15 * 128 + ((kk * 64 + lg * 16) ^ xr));
#pragma unroll
        for (int ct = 0; ct < 4; ct++) {
          int vrow = ct * 16 + l15;
          int cv = (kk * 4 + lg) ^ (vrow & 7);
          bf16x8 bv = *(const bf16x8*)((const char*)vt + vrow * 128 + cv * 16);
          accoB[ct] = mfma16(bv, ap, accoB[ct]);
        }
      }
    }

    // ---- A half (or its in-loop zero tile: keeps 8 stores/iter) ----
    if (n <= qtA) {
      f32x4 acc[4] = {};
      qk_tile(kb, aqA, acc);
      if (n == qtA) {
#pragma unroll
        for (int ct = 0; ct < 4; ct++) {
          int kb0 = k0 + ct * 16 + lg * 4;
#pragma unroll
          for (int j = 0; j < 4; j++)
            acc[ct][j] = (kb0 + j <= qrA) ? __builtin_amdgcn_exp2f(acc[ct][j]) * rinvA : 0.f;
        }
      } else {
#pragma unroll
        for (int ct = 0; ct < 4; ct++)
#pragma unroll
          for (int j = 0; j < 4; j++)
            acc[ct][j] = __builtin_amdgcn_exp2f(acc[ct][j]) * rinvA;
      }
      float* srow = SpA + (size_t)(w * 16 + l15) * 2048 + k0 + lg * 4;
#pragma unroll
      for (int ct = 0; ct < 4; ct++) *(f32x4*)(srow + ct * 16) = acc[ct];
#pragma unroll
      for (int ct = 0; ct < 4; ct++) {
        uint2 pw;
        pw.x = cvt_pk(acc[ct][0], acc[ct][1]);
        pw.y = cvt_pk(acc[ct][2], acc[ct][3]);
        *(uint2*)(myP + l15 * 128 + ((ct * 32 + lg * 8) ^ xr)) = pw;
      }
#pragma unroll
      for (int kk = 0; kk < 2; kk++) {
        bf16x8 ap = *(const bf16x8*)(myP + l15 * 128 + ((kk * 64 + lg * 16) ^ xr));
#pragma unroll
        for (int ct = 0; ct < 4; ct++) {
          int vrow = ct * 16 + l15;
          int cv = (kk * 4 + lg) ^ (vrow & 7);
          bf16x8 bv = *(const bf16x8*)((const char*)vt + vrow * 128 + cv * 16);
          accoA[ct] = mfma16(bv, ap, accoA[ct]);
        }
      }
    } else {
      f32x4 z = {0.f, 0.f, 0.f, 0.f};
      float* srow = SpA + (size_t)(w * 16 + l15) * 2048 + k0 + lg * 4;
#pragma unroll
      for (int ct = 0; ct < 4; ct++) *(f32x4*)(srow + ct * 16) = z;
    }
    // no bottom barrier: 4-buffer skew proof in header comment
  }

  // O stores: lane holds O[q=l15][d=ct*16+lg*4+..] -> packed uint2
  {
    int mA = b * 2048 + qtA * 64 + w * 16 + l15;
    int mB = b * 2048 + qtB * 64 + w * 16 + l15;
    unsigned int* oA = (unsigned int*)(attn_bf + (size_t)mA * 1024 + h * 64);
    unsigned int* oB = (unsigned int*)(attn_bf + (size_t)mB * 1024 + h * 64);
#pragma unroll
    for (int ct = 0; ct < 4; ct++) {
      uint2 pa, pb;
      pa.x = cvt_pk(accoA[ct][0], accoA[ct][1]);
      pa.y = cvt_pk(accoA[ct][2], accoA[ct][3]);
      pb.x = cvt_pk(accoB[ct][0], accoB[ct][1]);
      pb.y = cvt_pk(accoB[ct][2], accoB[ct][3]);
      *(uint2*)(oA + (ct * 16 + lg * 4) / 2) = pa;
      *(uint2*)(oB + (ct * 16 + lg * 4) / 2) = pb;
    }
  }

  // residual zero strip: cols [NB*64, 2048) for this lane's A and B rows
  int zbase = NB * 64;
  if (zbase < 2048) {
    f32x4 z = {0.f, 0.f, 0.f, 0.f};
    float* ra = scores + ((size_t)bh * 2048 + qrA) * 2048;
    float* rb = scores + ((size_t)bh * 2048 + qrB) * 2048;
    for (int c = zbase + lg * 4; c < 2048; c += 16) {
      *(f32x4*)(ra + c) = z;
      *(f32x4*)(rb + c) = z;
    }
  }
}

// ----------------------------------------------------------------- launch ---
extern "C" void kernel_launch(void* const* d_in, const int* in_sizes, int n_in,
                              void* d_out, int out_size, void* d_ws, size_t ws_size,
                              hipStream_t stream) {
  const float* hidden  = (const float*)d_in[0];
  // d_in[1] = mask: causal by construction; applied analytically.
  const float* scaling = (const float*)d_in[2];
  const float* qkv_w   = (const float*)d_in[3];
  const float* qkv_b   = (const float*)d_in[4];
  const float* o_w     = (const float*)d_in[5];
  const float* o_b     = (const float*)d_in[6];

  float* scores = (float*)d_out;                                 // [2][16][2048][2048]
  float* outp   = (float*)d_out + (size_t)2 * 16 * 2048 * 2048;  // [4096][1024]

  char* ws = (char*)d_ws;
  unsigned short* hidden_bf = (unsigned short*)(ws + 0);          //  8 MB
  unsigned short* qkvw_bf   = (unsigned short*)(ws + 8388608);    //  3 MB
  unsigned short* ow_bf     = (unsigned short*)(ws + 11534336);   //  2 MB
  unsigned short* q_ws      = (unsigned short*)(ws + 13631488);   //  8 MB
  unsigned short* k_ws      = (unsigned short*)(ws + 22020096);   //  2 MB
  unsigned short* v_ws      = (unsigned short*)(ws + 24117248);   //  2 MB
  unsigned short* attn_bf   = (unsigned short*)(ws + 26214400);   //  8 MB
  float* qscale             = (float*)(ws + 34603008);            //  256 B

  convert_kernel<<<512, 256, 0, stream>>>(hidden, qkv_w, o_w, scaling,
                                          hidden_bf, qkvw_bf, ow_bf, qscale);
  gemm_kernel<<<dim3(12, 32), 256, 0, stream>>>(hidden_bf, qkvw_bf, qkv_b,
                                                qscale, q_ws, k_ws, v_ws);
  attn_kernel<<<512, 256, 0, stream>>>(q_ws, k_ws, v_ws, scores, attn_bf);
  gemm2_kernel<<<dim3(8, 64), 256, 0, stream>>>(attn_bf, ow_bf, o_b, outp);
}

// Round 5
// 200.829 us; speedup vs baseline: 1.4136x; 1.0719x over previous
//
#include <hip/hip_runtime.h>
#include <hip/hip_bf16.h>
#include <cstdint>
#include <cstddef>

typedef __attribute__((ext_vector_type(4))) float f32x4;
typedef __attribute__((ext_vector_type(8))) short bf16x8;

#define DEVI static __device__ __forceinline__

DEVI unsigned short f2bf(float f) {
  union { float f; unsigned int u; } v; v.f = f;
  unsigned int u = v.u;
  unsigned int r = (u + 0x7fffu + ((u >> 16) & 1u)) >> 16;
  return (unsigned short)r;
}

// packed fp32 pair -> bf16x2 in one VALU op (RNE)
DEVI unsigned int cvt_pk(float lo, float hi) {
  unsigned int r;
  asm("v_cvt_pk_bf16_f32 %0, %1, %2" : "=v"(r) : "v"(lo), "v"(hi));
  return r;
}

DEVI f32x4 mfma16(bf16x8 a, bf16x8 b, f32x4 c) {
  return __builtin_amdgcn_mfma_f32_16x16x32_bf16(a, b, c, 0, 0, 0);
}

// global -> LDS direct staging, 16B per lane (wave-uniform LDS base).
#define GLDS(gp, lp) __builtin_amdgcn_global_load_lds(                         \
    (const __attribute__((address_space(1))) void*)(const void*)(gp),          \
    (__attribute__((address_space(3))) void*)(void*)(lp), 16, 0, 0)

#define SBAR() asm volatile("s_barrier" ::: "memory")
#define WV(n) asm volatile("s_waitcnt vmcnt(" #n ")" ::: "memory")
#define FORCE4(x) asm volatile("" : "+v"(x))

// ---------------------------------------------------------------- convert ---
__global__ void convert_kernel(const float* __restrict__ hidden,
                               const float* __restrict__ qkv_w,
                               const float* __restrict__ o_w,
                               const float* __restrict__ scaling,
                               unsigned short* __restrict__ hbf,
                               unsigned short* __restrict__ wbf,
                               unsigned short* __restrict__ obf,
                               float* __restrict__ qscale) {
  int tid = blockIdx.x * blockDim.x + threadIdx.x;
  int nt = gridDim.x * blockDim.x;
  if (tid < 64) {
    float x = scaling[tid];
    float sp = (x > 20.f) ? x : log1pf(__expf(x));
    // (1.442695041/8)*softplus, times log2e so softmax can use exp2 directly.
    qscale[tid] = 0.1803368801243369f * 1.4426950408889634f * sp;
  }
  for (int i = tid; i < 1048576; i += nt) {
    float4 v = ((const float4*)hidden)[i];
    ushort4 o = { f2bf(v.x), f2bf(v.y), f2bf(v.z), f2bf(v.w) };
    ((ushort4*)hbf)[i] = o;
  }
  for (int i = tid; i < 393216; i += nt) {
    float4 v = ((const float4*)qkv_w)[i];
    ushort4 o = { f2bf(v.x), f2bf(v.y), f2bf(v.z), f2bf(v.w) };
    ((ushort4*)wbf)[i] = o;
  }
  for (int i = tid; i < 262144; i += nt) {
    float4 v = ((const float4*)o_w)[i];
    ushort4 o = { f2bf(v.x), f2bf(v.y), f2bf(v.z), f2bf(v.w) };
    ((ushort4*)obf)[i] = o;
  }
}

// ------------------------------------------------------ GEMM 1 (qkv proj) ---
__global__ __launch_bounds__(256, 2) void gemm_kernel(
    const unsigned short* __restrict__ A,
    const unsigned short* __restrict__ Bw,
    const float* __restrict__ bias,
    const float* __restrict__ qscale,
    unsigned short* __restrict__ oq,
    unsigned short* __restrict__ okv,
    unsigned short* __restrict__ ovt) {
  __shared__ __align__(16) unsigned short sA[128 * 64];
  __shared__ __align__(16) unsigned short sB[128 * 64];
  const int t = threadIdx.x, lane = t & 63, w = t >> 6;
  const int l15 = lane & 15, lg = lane >> 4;
  const int m0 = blockIdx.y * 128, n0 = blockIdx.x * 128;
  const int wr = w >> 1, wc = w & 1;

  f32x4 acc[4][4] = {};

  for (int kb = 0; kb < 1024; kb += 64) {
    __syncthreads();
#pragma unroll
    for (int i = 0; i < 4; i++) {
      int idx = i * 256 + w * 64 + lane;
      int row = idx >> 3;
      int cg = (idx & 7) ^ (row & 7);
      GLDS(A + (size_t)(m0 + row) * 1024 + kb + cg * 8, sA + (i * 256 + w * 64) * 8);
      GLDS(Bw + (size_t)(n0 + row) * 1024 + kb + cg * 8, sB + (i * 256 + w * 64) * 8);
    }
    __syncthreads();
    bf16x8 af[4][2], bfr[4][2];
#pragma unroll
    for (int rt = 0; rt < 4; rt++) {
      int row = wr * 64 + rt * 16 + l15;
#pragma unroll
      for (int kk = 0; kk < 2; kk++) {
        int c = (kk * 4 + lg) ^ (row & 7);
        af[rt][kk] = *(const bf16x8*)((const char*)sA + row * 128 + c * 16);
      }
      int rowb = wc * 64 + rt * 16 + l15;
#pragma unroll
      for (int kk = 0; kk < 2; kk++) {
        int c = (kk * 4 + lg) ^ (rowb & 7);
        bfr[rt][kk] = *(const bf16x8*)((const char*)sB + rowb * 128 + c * 16);
      }
    }
#pragma unroll
    for (int kk = 0; kk < 2; kk++)
#pragma unroll
      for (int rt = 0; rt < 4; rt++)
#pragma unroll
        for (int ct = 0; ct < 4; ct++)
          acc[rt][ct] = mfma16(af[rt][kk], bfr[ct][kk], acc[rt][ct]);
  }

#pragma unroll
  for (int rt = 0; rt < 4; rt++) {
#pragma unroll
    for (int ct = 0; ct < 4; ct++) {
      int n = n0 + wc * 64 + ct * 16 + l15;
      float bv = bias[n];
#pragma unroll
      for (int jj = 0; jj < 4; jj++) {
        int m = m0 + wr * 64 + rt * 16 + lg * 4 + jj;
        float v = acc[rt][ct][jj] + bv;
        int b = m >> 11, s = m & 2047;
        if (n < 1024) {  // q: scaled, [b][h][s][d]
          int h = n >> 6, d = n & 63;
          v *= qscale[d];
          oq[(((size_t)(b * 16 + h) * 2048 + s) << 6) + d] = f2bf(v);
        } else if (n < 1280) {  // k: [b][kv][s][d]
          int kv = (n - 1024) >> 6, d = n & 63;
          okv[(((size_t)(b * 4 + kv) * 2048 + s) << 6) + d] = f2bf(v);
        } else {  // v transposed: [b][kv][d][s]
          int kv = (n - 1280) >> 6, d = n & 63;
          ovt[(((size_t)((b * 4 + kv) * 64 + d)) << 11) + s] = f2bf(v);
        }
      }
    }
  }
}

// ----------------------------------------------------- GEMM 2 (out proj) ----
// 64x128 tile -> grid (8,64) = 512 blocks = 2 blocks/CU.
__global__ __launch_bounds__(256, 2) void gemm2_kernel(
    const unsigned short* __restrict__ A,    // [4096][1024] bf16
    const unsigned short* __restrict__ Bw,   // [1024][1024] bf16 (o_w)
    const float* __restrict__ bias,
    float* __restrict__ of) {
  __shared__ __align__(16) unsigned short sA[64 * 64];
  __shared__ __align__(16) unsigned short sB[128 * 64];
  const int t = threadIdx.x, lane = t & 63, w = t >> 6;
  const int l15 = lane & 15, lg = lane >> 4;
  const int m0 = blockIdx.y * 64, n0 = blockIdx.x * 128;
  const int wr = w >> 1, wc = w & 1;  // 2x2 wave grid over 64x128

  f32x4 acc[2][4] = {};

  for (int kb = 0; kb < 1024; kb += 64) {
    __syncthreads();
#pragma unroll
    for (int i = 0; i < 2; i++) {
      int idx = i * 256 + w * 64 + lane;
      int row = idx >> 3;
      int cg = (idx & 7) ^ (row & 7);
      GLDS(A + (size_t)(m0 + row) * 1024 + kb + cg * 8, sA + (i * 256 + w * 64) * 8);
    }
#pragma unroll
    for (int i = 0; i < 4; i++) {
      int idx = i * 256 + w * 64 + lane;
      int row = idx >> 3;
      int cg = (idx & 7) ^ (row & 7);
      GLDS(Bw + (size_t)(n0 + row) * 1024 + kb + cg * 8, sB + (i * 256 + w * 64) * 8);
    }
    __syncthreads();
    bf16x8 af[2][2], bfr[4][2];
#pragma unroll
    for (int rt = 0; rt < 2; rt++) {
      int row = wr * 32 + rt * 16 + l15;
#pragma unroll
      for (int kk = 0; kk < 2; kk++) {
        int c = (kk * 4 + lg) ^ (row & 7);
        af[rt][kk] = *(const bf16x8*)((const char*)sA + row * 128 + c * 16);
      }
    }
#pragma unroll
    for (int ct = 0; ct < 4; ct++) {
      int rowb = wc * 64 + ct * 16 + l15;
#pragma unroll
      for (int kk = 0; kk < 2; kk++) {
        int c = (kk * 4 + lg) ^ (rowb & 7);
        bfr[ct][kk] = *(const bf16x8*)((const char*)sB + rowb * 128 + c * 16);
      }
    }
#pragma unroll
    for (int kk = 0; kk < 2; kk++)
#pragma unroll
      for (int rt = 0; rt < 2; rt++)
#pragma unroll
        for (int ct = 0; ct < 4; ct++)
          acc[rt][ct] = mfma16(af[rt][kk], bfr[ct][kk], acc[rt][ct]);
  }

#pragma unroll
  for (int rt = 0; rt < 2; rt++) {
#pragma unroll
    for (int ct = 0; ct < 4; ct++) {
      int n = n0 + wc * 64 + ct * 16 + l15;
      float bv = bias[n];
#pragma unroll
      for (int jj = 0; jj < 4; jj++) {
        int m = m0 + wr * 32 + rt * 16 + lg * 4 + jj;
        of[(size_t)m * 1024 + n] = acc[rt][ct][jj] + bv;
      }
    }
  }
}

// -------------------------------------------------------------- attention ---
// Fused-pair: block = (bh, p) handles q-tiles A=p and B=31-p with ONE K-sweep
// per pass. 4-buffer LDS, 2-deep prefetch, one barrier/iter, balanced p remap
// (round-3 structure; skew + vmcnt proofs below, unchanged).
//
// THIS REVISION (single change): per-block ROTATION of the k-tile visit
// order: n = (j + start) % NB, start = bid & 15 (< 17 <= NB always).
// Mechanism: scores rows are 8KB (2^13) apart; within a wave-store the 16
// lanes differ only by l15*8KB, so the HBM channel is selected by the k0
// column window alone. With all 512 blocks sweeping k0 in lockstep from 0,
// every block's stores camp on the same few channels simultaneously
// (rotating slowly) -> ~half write BW. The rotation gives 16 distinct 256B
// start windows (4KB span) so concurrent blocks spread across the channel
// hash. Masks/rowsums/PV depend only on n (commutative); buffers and vmcnt
// depend only on j (queue shape unchanged: pass2 is uniformly 8 stores/iter
// since A-inactive iters store a zero tile instead).
//
//  * Skew proof: barrier at top of iter j ensures all waves finished iter j-1
//    compute. Fastest wave at iter j stages buf (j+2)&3; slowest may still
//    read buf (j-1)&3 or j&3 -> distinct mod 4.
//  * vmcnt pass 1 (2 GLDS/iter, no stores): steady WV(4); tail WV(2)/WV(0).
//    pass 2 (4 GLDS + 8 stores/iter): steady WV(24) =
//    S_{j-2}(8)+G_{j+1}(4)+S_{j-1}(8)+G_{j+2}(4); j=0 -> 8, j=1 -> 16,
//    j=NB-2 -> 20, j=NB-1 -> 16.
__global__ __launch_bounds__(256, 2) void attn_kernel(
    const unsigned short* __restrict__ q_ws,
    const unsigned short* __restrict__ k_ws,
    const unsigned short* __restrict__ v_ws,
    float* __restrict__ scores,
    unsigned short* __restrict__ attn_bf) {
  __shared__ __align__(16) unsigned short sK[4][4096];
  __shared__ __align__(16) unsigned short sVT[4][4096];
  __shared__ __align__(16) unsigned char sP[4][2048];

  const int t = threadIdx.x, lane = t & 63, w = t >> 6;
  const int l15 = lane & 15, lg = lane >> 4;
  int bid = blockIdx.x;
  int bh = bid & 31;            // b*16+h
  int pr = bid >> 5;            // 0..15
  int p = (bid < 256) ? pr : (23 - pr);  // balance: bid & bid+256 -> p & 15-p
  int b = bh >> 4, h = bh & 15, kv = h >> 2;
  const int qtA = p, qtB = 31 - p;
  const int NB = qtB + 1;       // 17..32 k-tiles (covers A's p+1)
  const int start = bid & 15;   // rotation offset, always < NB

  const unsigned short* Kp = k_ws + ((size_t)(b * 4 + kv) * 2048) * 64;
  const unsigned short* Vp = v_ws + ((size_t)(b * 4 + kv) * 64) * 2048;  // [d][s]
  const int qrA = qtA * 64 + w * 16 + l15;   // this lane's A q-row
  const int qrB = qtB * 64 + w * 16 + l15;   // this lane's B q-row

  auto rot = [&](int j) { int n = j + start; return (n >= NB) ? n - NB : n; };

  // per-lane Q fragments (compiler-tracked; FORCE4 drains them before staging)
  bf16x8 aqA[2], aqB[2];
  {
    const unsigned short* qa = q_ws + ((size_t)bh * 2048 + qrA) * 64;
    const unsigned short* qb = q_ws + ((size_t)bh * 2048 + qrB) * 64;
    aqA[0] = *(const bf16x8*)(qa + lg * 8);
    aqA[1] = *(const bf16x8*)(qa + 32 + lg * 8);
    aqB[0] = *(const bf16x8*)(qb + lg * 8);
    aqB[1] = *(const bf16x8*)(qb + 32 + lg * 8);
    FORCE4(*(f32x4*)&aqA[0]); FORCE4(*(f32x4*)&aqA[1]);
    FORCE4(*(f32x4*)&aqB[0]); FORCE4(*(f32x4*)&aqB[1]);
  }

  auto stageK = [&](int kt, int bufi) {  // 2 GLDS per wave
#pragma unroll
    for (int i = 0; i < 2; i++) {
      int idx = i * 256 + w * 64 + lane;
      int row = idx >> 3;
      int cg = (idx & 7) ^ (row & 7);
      GLDS(Kp + (size_t)(kt * 64 + row) * 64 + cg * 8, sK[bufi] + (i * 256 + w * 64) * 8);
    }
  };
  auto stageVT = [&](int kt, int bufi) {  // 2 GLDS per wave
#pragma unroll
    for (int i = 0; i < 2; i++) {
      int idx = i * 256 + w * 64 + lane;
      int row = idx >> 3;
      int cg = (idx & 7) ^ (row & 7);
      GLDS(Vp + (size_t)row * 2048 + kt * 64 + cg * 8, sVT[bufi] + (i * 256 + w * 64) * 8);
    }
  };
  // swapped QK^T: K rows as A, Q as B -> acc[ct][j] = S[q=l15][k0+ct*16+lg*4+j]
  auto qk_tile = [&](const unsigned short* kb, const bf16x8(&aq)[2], f32x4(&acc)[4]) {
#pragma unroll
    for (int ct = 0; ct < 4; ct++) {
      int row = ct * 16 + l15;
#pragma unroll
      for (int kk = 0; kk < 2; kk++) {
        int c = (kk * 4 + lg) ^ (row & 7);
        bf16x8 ak = *(const bf16x8*)((const char*)kb + row * 128 + c * 16);
        acc[ct] = mfma16(ak, aq[kk], acc[ct]);
      }
    }
  };

  // ---- pass 1: rowsums for BOTH halves, rotated K sweep, 2-deep prefetch ----
  stageK(rot(0), 0);
  stageK(rot(1), 1);
  float rsA = 0.f, rsB = 0.f;
  for (int j = 0; j < NB; j++) {
    const int n = rot(j);
    if (j + 2 < NB) { stageK(rot(j + 2), (j + 2) & 3); WV(4); }
    else if (j + 1 < NB) { WV(2); }
    else { WV(0); }
    SBAR();
    const unsigned short* kb = sK[j & 3];
    {
      f32x4 acc[4] = {};
      qk_tile(kb, aqB, acc);
      if (n < NB - 1) {
#pragma unroll
        for (int ct = 0; ct < 4; ct++)
#pragma unroll
          for (int jj = 0; jj < 4; jj++) rsB += __builtin_amdgcn_exp2f(acc[ct][jj]);
      } else {
#pragma unroll
        for (int ct = 0; ct < 4; ct++) {
          int kb0 = n * 64 + ct * 16 + lg * 4;
#pragma unroll
          for (int jj = 0; jj < 4; jj++)
            rsB += (kb0 + jj <= qrB) ? __builtin_amdgcn_exp2f(acc[ct][jj]) : 0.f;
        }
      }
    }
    if (n <= qtA) {
      f32x4 acc[4] = {};
      qk_tile(kb, aqA, acc);
      if (n < qtA) {
#pragma unroll
        for (int ct = 0; ct < 4; ct++)
#pragma unroll
          for (int jj = 0; jj < 4; jj++) rsA += __builtin_amdgcn_exp2f(acc[ct][jj]);
      } else {
#pragma unroll
        for (int ct = 0; ct < 4; ct++) {
          int kb0 = n * 64 + ct * 16 + lg * 4;
#pragma unroll
          for (int jj = 0; jj < 4; jj++)
            rsA += (kb0 + jj <= qrA) ? __builtin_amdgcn_exp2f(acc[ct][jj]) : 0.f;
        }
      }
    }
    // no bottom barrier: 4-buffer skew proof in header comment
  }
  rsA += __shfl_xor(rsA, 16); rsA += __shfl_xor(rsA, 32);
  rsB += __shfl_xor(rsB, 16); rsB += __shfl_xor(rsB, 32);
  float rinvA = 1.0f / rsA, rinvB = 1.0f / rsB;

  SBAR();  // pass-1 readers done before pass-2 staging reuses buffers

  // ---- pass 2: P stores + in-loop zeros + PV, rotated, 2-deep prefetch ----
  stageK(rot(0), 0); stageVT(rot(0), 0);
  stageK(rot(1), 1); stageVT(rot(1), 1);
  f32x4 accoA[4] = {}, accoB[4] = {};
  unsigned char* myP = &sP[w][0];
  const int xr = (l15 & 7) << 4;
  float* SpA = scores + ((size_t)bh * 2048 + qtA * 64) * 2048;
  float* SpB = scores + ((size_t)bh * 2048 + qtB * 64) * 2048;

  for (int j = 0; j < NB; j++) {
    const int n = rot(j);
    if (j + 2 < NB) { stageK(rot(j + 2), (j + 2) & 3); stageVT(rot(j + 2), (j + 2) & 3); }
    if (j == 0) { WV(8); }
    else if (j == 1) { WV(16); }
    else if (j + 2 < NB) { WV(24); }
    else if (j + 1 < NB) { WV(20); }
    else { WV(16); }
    SBAR();
    const unsigned short* kb = sK[j & 3];
    const unsigned short* vt = sVT[j & 3];
    int k0 = n * 64;

    // ---- B half ----
    {
      f32x4 acc[4] = {};
      qk_tile(kb, aqB, acc);
      if (n == NB - 1) {
#pragma unroll
        for (int ct = 0; ct < 4; ct++) {
          int kb0 = k0 + ct * 16 + lg * 4;
#pragma unroll
          for (int jj = 0; jj < 4; jj++)
            acc[ct][jj] = (kb0 + jj <= qrB) ? __builtin_amdgcn_exp2f(acc[ct][jj]) * rinvB : 0.f;
        }
      } else {
#pragma unroll
        for (int ct = 0; ct < 4; ct++)
#pragma unroll
          for (int jj = 0; jj < 4; jj++)
            acc[ct][jj] = __builtin_amdgcn_exp2f(acc[ct][jj]) * rinvB;
      }
      float* srow = SpB + (size_t)(w * 16 + l15) * 2048 + k0 + lg * 4;
#pragma unroll
      for (int ct = 0; ct < 4; ct++) *(f32x4*)(srow + ct * 16) = acc[ct];
#pragma unroll
      for (int ct = 0; ct < 4; ct++) {
        uint2 pw;
        pw.x = cvt_pk(acc[ct][0], acc[ct][1]);
        pw.y = cvt_pk(acc[ct][2], acc[ct][3]);
        *(uint2*)(myP + l15 * 128 + ((ct * 32 + lg * 8) ^ xr)) = pw;
      }
#pragma unroll
      for (int kk = 0; kk < 2; kk++) {
        bf16x8 ap = *(const bf16x8*)(myP + l15 * 128 + ((kk * 64 + lg * 16) ^ xr));
#pragma unroll
        for (int ct = 0; ct < 4; ct++) {
          int vrow = ct * 16 + l15;
          int cv = (kk * 4 + lg) ^ (vrow & 7);
          bf16x8 bv = *(const bf16x8*)((const char*)vt + vrow * 128 + cv * 16);
          accoB[ct] = mfma16(bv, ap, accoB[ct]);
        }
      }
    }

    // ---- A half (or its zero tile: keeps 8 stores/iter uniform) ----
    if (n <= qtA) {
      f32x4 acc[4] = {};
      qk_tile(kb, aqA, acc);
      if (n == qtA) {
#pragma unroll
        for (int ct = 0; ct < 4; ct++) {
          int kb0 = k0 + ct * 16 + lg * 4;
#pragma unroll
          for (int jj = 0; jj < 4; jj++)
            acc[ct][jj] = (kb0 + jj <= qrA) ? __builtin_amdgcn_exp2f(acc[ct][jj]) * rinvA : 0.f;
        }
      } else {
#pragma unroll
        for (int ct = 0; ct < 4; ct++)
#pragma unroll
          for (int jj = 0; jj < 4; jj++)
            acc[ct][jj] = __builtin_amdgcn_exp2f(acc[ct][jj]) * rinvA;
      }
      float* srow = SpA + (size_t)(w * 16 + l15) * 2048 + k0 + lg * 4;
#pragma unroll
      for (int ct = 0; ct < 4; ct++) *(f32x4*)(srow + ct * 16) = acc[ct];
#pragma unroll
      for (int ct = 0; ct < 4; ct++) {
        uint2 pw;
        pw.x = cvt_pk(acc[ct][0], acc[ct][1]);
        pw.y = cvt_pk(acc[ct][2], acc[ct][3]);
        *(uint2*)(myP + l15 * 128 + ((ct * 32 + lg * 8) ^ xr)) = pw;
      }
#pragma unroll
      for (int kk = 0; kk < 2; kk++) {
        bf16x8 ap = *(const bf16x8*)(myP + l15 * 128 + ((kk * 64 + lg * 16) ^ xr));
#pragma unroll
        for (int ct = 0; ct < 4; ct++) {
          int vrow = ct * 16 + l15;
          int cv = (kk * 4 + lg) ^ (vrow & 7);
          bf16x8 bv = *(const bf16x8*)((const char*)vt + vrow * 128 + cv * 16);
          accoA[ct] = mfma16(bv, ap, accoA[ct]);
        }
      }
    } else {
      f32x4 z = {0.f, 0.f, 0.f, 0.f};
      float* srow = SpA + (size_t)(w * 16 + l15) * 2048 + k0 + lg * 4;
#pragma unroll
      for (int ct = 0; ct < 4; ct++) *(f32x4*)(srow + ct * 16) = z;
    }
    // no bottom barrier: 4-buffer skew proof in header comment
  }

  // O stores: lane holds O[q=l15][d=ct*16+lg*4+..] -> packed uint2
  {
    int mA = b * 2048 + qtA * 64 + w * 16 + l15;
    int mB = b * 2048 + qtB * 64 + w * 16 + l15;
    unsigned int* oA = (unsigned int*)(attn_bf + (size_t)mA * 1024 + h * 64);
    unsigned int* oB = (unsigned int*)(attn_bf + (size_t)mB * 1024 + h * 64);
#pragma unroll
    for (int ct = 0; ct < 4; ct++) {
      uint2 pa, pb;
      pa.x = cvt_pk(accoA[ct][0], accoA[ct][1]);
      pa.y = cvt_pk(accoA[ct][2], accoA[ct][3]);
      pb.x = cvt_pk(accoB[ct][0], accoB[ct][1]);
      pb.y = cvt_pk(accoB[ct][2], accoB[ct][3]);
      *(uint2*)(oA + (ct * 16 + lg * 4) / 2) = pa;
      *(uint2*)(oB + (ct * 16 + lg * 4) / 2) = pb;
    }
  }

  // residual zero strip: cols [NB*64, 2048) for this lane's A and B rows
  int zbase = NB * 64;
  if (zbase < 2048) {
    f32x4 z = {0.f, 0.f, 0.f, 0.f};
    float* ra = scores + ((size_t)bh * 2048 + qrA) * 2048;
    float* rb = scores + ((size_t)bh * 2048 + qrB) * 2048;
    for (int c = zbase + lg * 4; c < 2048; c += 16) {
      *(f32x4*)(ra + c) = z;
      *(f32x4*)(rb + c) = z;
    }
  }
}

// ----------------------------------------------------------------- launch ---
extern "C" void kernel_launch(void* const* d_in, const int* in_sizes, int n_in,
                              void* d_out, int out_size, void* d_ws, size_t ws_size,
                              hipStream_t stream) {
  const float* hidden  = (const float*)d_in[0];
  // d_in[1] = mask: causal by construction; applied analytically.
  const float* scaling = (const float*)d_in[2];
  const float* qkv_w   = (const float*)d_in[3];
  const float* qkv_b   = (const float*)d_in[4];
  const float* o_w     = (const float*)d_in[5];
  const float* o_b     = (const float*)d_in[6];

  float* scores = (float*)d_out;                                 // [2][16][2048][2048]
  float* outp   = (float*)d_out + (size_t)2 * 16 * 2048 * 2048;  // [4096][1024]

  char* ws = (char*)d_ws;
  unsigned short* hidden_bf = (unsigned short*)(ws + 0);          //  8 MB
  unsigned short* qkvw_bf   = (unsigned short*)(ws + 8388608);    //  3 MB
  unsigned short* ow_bf     = (unsigned short*)(ws + 11534336);   //  2 MB
  unsigned short* q_ws      = (unsigned short*)(ws + 13631488);   //  8 MB
  unsigned short* k_ws      = (unsigned short*)(ws + 22020096);   //  2 MB
  unsigned short* v_ws      = (unsigned short*)(ws + 24117248);   //  2 MB
  unsigned short* attn_bf   = (unsigned short*)(ws + 26214400);   //  8 MB
  float* qscale             = (float*)(ws + 34603008);            //  256 B

  convert_kernel<<<512, 256, 0, stream>>>(hidden, qkv_w, o_w, scaling,
                                          hidden_bf, qkvw_bf, ow_bf, qscale);
  gemm_kernel<<<dim3(12, 32), 256, 0, stream>>>(hidden_bf, qkvw_bf, qkv_b,
                                                qscale, q_ws, k_ws, v_ws);
  attn_kernel<<<512, 256, 0, stream>>>(q_ws, k_ws, v_ws, scores, attn_bf);
  gemm2_kernel<<<dim3(8, 64), 256, 0, stream>>>(attn_bf, ow_bf, o_b, outp);
}